// Round 1
// baseline (4710.565 us; speedup 1.0000x reference)
//
#include <hip/hip_runtime.h>
#include <math.h>

#define HDIM 128
#define RDIM 20
#define TE 64

__device__ __forceinline__ float silu_f(float v) { return v / (1.0f + __expf(-v)); }

// ---------------------------------------------------------------------------
// Generic tiled f32 GEMM: C[M,Nc] = act(A[M,K] @ W[K,Nc] + bias)
// block 256, BM=64, BN=128, BK=32, 4x8 micro-tile per thread.
// Requires K % 32 == 0, Nc % 128 == 0.
// ---------------------------------------------------------------------------
template<bool SILU, bool HASBIAS>
__global__ __launch_bounds__(256) void gemm_kernel(
    const float* __restrict__ A, const float* __restrict__ W,
    const float* __restrict__ bias, float* __restrict__ C,
    int M, int K, int Nc)
{
    __shared__ float As[64 * 33];     // padded stride 33 -> conflict-free
    __shared__ float Wsl[32 * 128];
    const int t = threadIdx.x;
    const int row0 = blockIdx.x * 64;
    const int col0 = blockIdx.y * 128;
    const int tj = t & 15, ti = t >> 4;
    const int j0 = tj * 8, i0 = ti * 4;
    float acc[4][8];
#pragma unroll
    for (int r = 0; r < 4; ++r)
#pragma unroll
        for (int c = 0; c < 8; ++c) acc[r][c] = 0.f;

    const int nkb = K >> 5;
    for (int kb = 0; kb < nkb; ++kb) {
#pragma unroll
        for (int v = 0; v < 2; ++v) {         // A tile 64x32 = 512 float4
            int qq = v * 256 + t;
            int i = qq >> 3;
            int kv = (qq & 7) << 2;
            int row = row0 + i;
            float4 f = make_float4(0.f, 0.f, 0.f, 0.f);
            if (row < M) f = *(const float4*)&A[(size_t)row * K + kb * 32 + kv];
            float* dst = &As[i * 33 + kv];
            dst[0] = f.x; dst[1] = f.y; dst[2] = f.z; dst[3] = f.w;
        }
#pragma unroll
        for (int v = 0; v < 4; ++v) {         // W slice 32x128 = 1024 float4
            int qq = v * 256 + t;
            int kk = qq >> 5;
            int jv = (qq & 31) << 2;
            *(float4*)&Wsl[kk * 128 + jv] =
                *(const float4*)&W[(size_t)(kb * 32 + kk) * Nc + col0 + jv];
        }
        __syncthreads();
#pragma unroll
        for (int kk = 0; kk < 32; ++kk) {
            float4 w0 = *(float4*)&Wsl[kk * 128 + j0];
            float4 w1 = *(float4*)&Wsl[kk * 128 + j0 + 4];
#pragma unroll
            for (int r = 0; r < 4; ++r) {
                float a = As[(i0 + r) * 33 + kk];
                acc[r][0] += a * w0.x; acc[r][1] += a * w0.y;
                acc[r][2] += a * w0.z; acc[r][3] += a * w0.w;
                acc[r][4] += a * w1.x; acc[r][5] += a * w1.y;
                acc[r][6] += a * w1.z; acc[r][7] += a * w1.w;
            }
        }
        __syncthreads();
    }
#pragma unroll
    for (int r = 0; r < 4; ++r) {
        int row = row0 + i0 + r;
        if (row >= M) continue;
        float out[8];
#pragma unroll
        for (int c = 0; c < 8; ++c) {
            float v = acc[r][c];
            if (HASBIAS) v += bias[col0 + j0 + c];
            if (SILU) v = silu_f(v);
            out[c] = v;
        }
        float* cp = &C[(size_t)row * Nc + col0 + j0];
        *(float4*)&cp[0] = make_float4(out[0], out[1], out[2], out[3]);
        *(float4*)&cp[4] = make_float4(out[4], out[5], out[6], out[7]);
    }
}

// ---------------------------------------------------------------------------
// Degree histogram
// ---------------------------------------------------------------------------
__global__ void deg_kernel(const int* __restrict__ ei, float* __restrict__ deg, int E) {
    int e = blockIdx.x * 256 + threadIdx.x;
    if (e < E) atomicAdd(&deg[ei[e]], 1.0f);
}

// ---------------------------------------------------------------------------
// Fused edge kernel: computes per-edge filters on the fly
//   h      = silu(rbf @ Wf1 + bf1)                [64 edges x 128] in LDS
//   F      = (h @ Wf2 + bf2) * cutoff             (3 chunks of 128 cols)
// then scatters scalar & vector messages with atomics.
// ---------------------------------------------------------------------------
__global__ __launch_bounds__(256) void edge_kernel(
    const int* __restrict__ ei, const float* __restrict__ rbf,
    const float* __restrict__ uv, const float* __restrict__ cutv,
    const float* __restrict__ Wf1, const float* __restrict__ bf1,
    const float* __restrict__ Wf2, const float* __restrict__ bf2,
    const float* __restrict__ x, const float* __restrict__ mu,
    float* __restrict__ scalar_msg, float* __restrict__ vector_msg,
    int E)
{
    __shared__ float s_rbf[TE * RDIM];
    __shared__ float s_h[TE * 132];        // stride 132: conflict-free row reads
    __shared__ float s_w[2 * 32 * 128];    // Wf2 slices
    __shared__ int   s_src[TE];
    __shared__ int   s_tgt[TE];
    __shared__ float s_cut[TE];
    __shared__ float s_uv[TE * 3];

    const int t = threadIdx.x;
    const int e0 = blockIdx.x * TE;

    // ---- phase 1: load per-edge metadata ----
    for (int qq = t; qq < TE * RDIM; qq += 256) {
        int e = e0 + qq / RDIM;
        s_rbf[qq] = (e < E) ? rbf[(size_t)e0 * RDIM + qq] : 0.f;
    }
    for (int qq = t; qq < TE * 3; qq += 256) {
        int e = e0 + qq / 3;
        s_uv[qq] = (e < E) ? uv[(size_t)e0 * 3 + qq] : 0.f;
    }
    if (t < TE) {
        int e = e0 + t;
        bool v = (e < E);
        s_tgt[t] = v ? ei[e] : 0;
        s_src[t] = v ? ei[(size_t)E + e] : 0;
        s_cut[t] = v ? cutv[e] : 0.f;
    }
    __syncthreads();

    // ---- phase 2: h = silu(rbf @ Wf1 + bf1) ----
    for (int qq = t; qq < TE * HDIM; qq += 256) {
        int i = qq >> 7, k = qq & 127;
        float a = bf1[k];
#pragma unroll
        for (int r = 0; r < RDIM; ++r) a += s_rbf[i * RDIM + r] * Wf1[r * HDIM + k];
        s_h[i * 132 + k] = silu_f(a);
    }
    __syncthreads();

    const int tj = t & 15, ti = t >> 4;
    const int j0 = tj * 8, i0 = ti * 4;

    // ================= pass A: filter_q -> scalar messages =================
    float accq[4][8];
#pragma unroll
    for (int r = 0; r < 4; ++r)
#pragma unroll
        for (int c = 0; c < 8; ++c) accq[r][c] = 0.f;

    for (int kb = 0; kb < 4; ++kb) {
#pragma unroll
        for (int v = 0; v < 4; ++v) {
            int qq = v * 256 + t;
            int kk = qq >> 5, jv = (qq & 31) << 2;
            *(float4*)&s_w[kk * 128 + jv] =
                *(const float4*)&Wf2[(size_t)(kb * 32 + kk) * 384 + jv];
        }
        __syncthreads();
#pragma unroll
        for (int kk = 0; kk < 32; ++kk) {
            float4 w0 = *(float4*)&s_w[kk * 128 + j0];
            float4 w1 = *(float4*)&s_w[kk * 128 + j0 + 4];
            int kg = kb * 32 + kk;
#pragma unroll
            for (int r = 0; r < 4; ++r) {
                float a = s_h[(i0 + r) * 132 + kg];
                accq[r][0] += a * w0.x; accq[r][1] += a * w0.y;
                accq[r][2] += a * w0.z; accq[r][3] += a * w0.w;
                accq[r][4] += a * w1.x; accq[r][5] += a * w1.y;
                accq[r][6] += a * w1.z; accq[r][7] += a * w1.w;
            }
        }
        __syncthreads();
    }
    {
        float bq[8];
#pragma unroll
        for (int c = 0; c < 8; ++c) bq[c] = bf2[j0 + c];
#pragma unroll
        for (int r = 0; r < 4; ++r) {
            int i = i0 + r;
            if (e0 + i >= E) continue;
            int s = s_src[i], tg = s_tgt[i];
            float cu = s_cut[i];
            const float* xp = &x[(size_t)s * 384 + j0];
            float4 x0 = *(const float4*)&xp[0];
            float4 x1 = *(const float4*)&xp[4];
            float xv[8] = {x0.x, x0.y, x0.z, x0.w, x1.x, x1.y, x1.z, x1.w};
            float* sm = &scalar_msg[(size_t)tg * HDIM + j0];
#pragma unroll
            for (int c = 0; c < 8; ++c)
                atomicAdd(&sm[c], (accq[r][c] + bq[c]) * cu * xv[c]);
        }
    }

    // ============ pass B: filter_r & filter_mu -> vector messages ==========
    float accr[4][8], accm[4][8];
#pragma unroll
    for (int r = 0; r < 4; ++r)
#pragma unroll
        for (int c = 0; c < 8; ++c) { accr[r][c] = 0.f; accm[r][c] = 0.f; }

    for (int kb = 0; kb < 4; ++kb) {
#pragma unroll
        for (int v = 0; v < 8; ++v) {
            int qq = v * 256 + t;          // 0..2047
            int half = qq >> 10;
            int rem = qq & 1023;
            int kk = rem >> 5, jv = (rem & 31) << 2;
            *(float4*)&s_w[half * 4096 + kk * 128 + jv] =
                *(const float4*)&Wf2[(size_t)(kb * 32 + kk) * 384 + 128 + half * 128 + jv];
        }
        __syncthreads();
#pragma unroll
        for (int kk = 0; kk < 32; ++kk) {
            float4 w0 = *(float4*)&s_w[kk * 128 + j0];
            float4 w1 = *(float4*)&s_w[kk * 128 + j0 + 4];
            float4 w2 = *(float4*)&s_w[4096 + kk * 128 + j0];
            float4 w3 = *(float4*)&s_w[4096 + kk * 128 + j0 + 4];
            int kg = kb * 32 + kk;
#pragma unroll
            for (int r = 0; r < 4; ++r) {
                float a = s_h[(i0 + r) * 132 + kg];
                accr[r][0] += a * w0.x; accr[r][1] += a * w0.y;
                accr[r][2] += a * w0.z; accr[r][3] += a * w0.w;
                accr[r][4] += a * w1.x; accr[r][5] += a * w1.y;
                accr[r][6] += a * w1.z; accr[r][7] += a * w1.w;
                accm[r][0] += a * w2.x; accm[r][1] += a * w2.y;
                accm[r][2] += a * w2.z; accm[r][3] += a * w2.w;
                accm[r][4] += a * w3.x; accm[r][5] += a * w3.y;
                accm[r][6] += a * w3.z; accm[r][7] += a * w3.w;
            }
        }
        __syncthreads();
    }
    {
        float br[8], bm[8];
#pragma unroll
        for (int c = 0; c < 8; ++c) { br[c] = bf2[128 + j0 + c]; bm[c] = bf2[256 + j0 + c]; }
#pragma unroll
        for (int r = 0; r < 4; ++r) {
            int i = i0 + r;
            if (e0 + i >= E) continue;
            int s = s_src[i], tg = s_tgt[i];
            float cu = s_cut[i];
            float ux = s_uv[i * 3], uyy = s_uv[i * 3 + 1], uzz = s_uv[i * 3 + 2];
            const float* xb = &x[(size_t)s * 384];
            float4 a0 = *(const float4*)&xb[128 + j0];
            float4 a1 = *(const float4*)&xb[128 + j0 + 4];
            float4 b0 = *(const float4*)&xb[256 + j0];
            float4 b1 = *(const float4*)&xb[256 + j0 + 4];
            float xr[8] = {a0.x, a0.y, a0.z, a0.w, a1.x, a1.y, a1.z, a1.w};
            float xm[8] = {b0.x, b0.y, b0.z, b0.w, b1.x, b1.y, b1.z, b1.w};
            const float* mub = &mu[(size_t)s * 384 + j0];
            float4 m00 = *(const float4*)&mub[0];   float4 m01 = *(const float4*)&mub[4];
            float4 m10 = *(const float4*)&mub[128]; float4 m11 = *(const float4*)&mub[132];
            float4 m20 = *(const float4*)&mub[256]; float4 m21 = *(const float4*)&mub[260];
            float mu0[8] = {m00.x, m00.y, m00.z, m00.w, m01.x, m01.y, m01.z, m01.w};
            float mu1[8] = {m10.x, m10.y, m10.z, m10.w, m11.x, m11.y, m11.z, m11.w};
            float mu2[8] = {m20.x, m20.y, m20.z, m20.w, m21.x, m21.y, m21.z, m21.w};
            float* vmp = &vector_msg[(size_t)tg * 384 + j0];
#pragma unroll
            for (int c = 0; c < 8; ++c) {
                float vr = (accr[r][c] + br[c]) * cu * xr[c];
                float vm = (accm[r][c] + bm[c]) * cu * xm[c];
                atomicAdd(&vmp[c],       ux  * vr + mu0[c] * vm);
                atomicAdd(&vmp[128 + c], uyy * vr + mu1[c] * vm);
                atomicAdd(&vmp[256 + c], uzz * vr + mu2[c] * vm);
            }
        }
    }
}

// ---------------------------------------------------------------------------
// q_new = q + scalar/deg ; mu_new = mu + vec/deg   (written into d_out)
// ---------------------------------------------------------------------------
__global__ void node_update_kernel(const float* __restrict__ q, const float* __restrict__ mu,
    const float* __restrict__ scalar_msg, const float* __restrict__ vector_msg,
    const float* __restrict__ deg, float* __restrict__ outq, float* __restrict__ outmu, int N)
{
    int idx = blockIdx.x * 256 + threadIdx.x;
    if (idx >= N * HDIM) return;
    int n = idx >> 7, k = idx & 127;
    float inv = 1.0f / fmaxf(deg[n], 1.0f);
    outq[idx] = q[idx] + scalar_msg[idx] * inv;
#pragma unroll
    for (int c = 0; c < 3; ++c) {
        size_t o = ((size_t)n * 3 + c) * HDIM + k;
        outmu[o] = mu[o] + vector_msg[o] * inv;
    }
}

// ---------------------------------------------------------------------------
// scalar_input = [q_new, ||mu_v||]
// ---------------------------------------------------------------------------
__global__ void si_kernel(const float* __restrict__ outq, const float* __restrict__ mu_cat,
                          float* __restrict__ si, int N)
{
    int idx = blockIdx.x * 256 + threadIdx.x;
    if (idx >= N * 256) return;
    int n = idx >> 8, j = idx & 255;
    if (j < 128) {
        si[idx] = outq[n * 128 + j];
    } else {
        int k = j - 128;
        float s2 = 1e-8f;
#pragma unroll
        for (int c = 0; c < 3; ++c) {
            float v = mu_cat[((size_t)n * 3 + c) * 256 + k];
            s2 += v * v;
        }
        si[idx] = sqrtf(s2);
    }
}

// ---------------------------------------------------------------------------
// final: q += dq + dqmu*inner ; mu += mu_w * dmu_scale
// ---------------------------------------------------------------------------
__global__ void final_kernel(const float* __restrict__ mu_cat, const float* __restrict__ delta,
                             float* __restrict__ outq, float* __restrict__ outmu, int N)
{
    int idx = blockIdx.x * 256 + threadIdx.x;
    if (idx >= N * HDIM) return;
    int n = idx >> 7, k = idx & 127;
    float inner = 0.f, mw[3];
#pragma unroll
    for (int c = 0; c < 3; ++c) {
        float mv = mu_cat[((size_t)n * 3 + c) * 256 + k];
        mw[c] = mu_cat[((size_t)n * 3 + c) * 256 + 128 + k];
        inner += mv * mw[c];
    }
    const float* dl = &delta[(size_t)n * 384];
    float dq = dl[k], dsc = dl[128 + k], dqm = dl[256 + k];
    outq[idx] += dq + dqm * inner;
#pragma unroll
    for (int c = 0; c < 3; ++c) {
        size_t o = ((size_t)n * 3 + c) * HDIM + k;
        outmu[o] += mw[c] * dsc;
    }
}

// ---------------------------------------------------------------------------
extern "C" void kernel_launch(void* const* d_in, const int* in_sizes, int n_in,
                              void* d_out, int out_size, void* d_ws, size_t ws_size,
                              hipStream_t stream)
{
    const float* q    = (const float*)d_in[0];
    const float* mu   = (const float*)d_in[1];
    const int*   ei   = (const int*)d_in[2];
    const float* rbf  = (const float*)d_in[3];
    const float* uv   = (const float*)d_in[4];
    const float* cutv = (const float*)d_in[5];
    const float* Wi1  = (const float*)d_in[6];
    const float* bi1  = (const float*)d_in[7];
    const float* Wi2  = (const float*)d_in[8];
    const float* bi2  = (const float*)d_in[9];
    const float* Wf1  = (const float*)d_in[10];
    const float* bf1  = (const float*)d_in[11];
    const float* Wf2  = (const float*)d_in[12];
    const float* bf2  = (const float*)d_in[13];
    const float* Wv   = (const float*)d_in[14];
    const float* Ws1  = (const float*)d_in[15];
    const float* bs1  = (const float*)d_in[16];
    const float* Ws2  = (const float*)d_in[17];
    const float* bs2  = (const float*)d_in[18];

    const int N = in_sizes[0] / HDIM;     // 10000
    const int E = in_sizes[2] / 2;        // 320000

    float* ws = (float*)d_ws;
    // region 0: [0, 513N) : scalar_msg(128N) | vector_msg(384N) | deg(N); reused by t2
    float* scalar_msg = ws;
    float* vector_msg = ws + (size_t)N * 128;
    float* deg        = ws + (size_t)N * 512;
    float* t2         = ws;                        // reuse after messages consumed
    // region 1: [513N, 897N): x ; reused by si
    float* xbuf       = ws + (size_t)N * 513;
    float* si         = xbuf;
    // region 2: [897N, 1281N): t1 ; reused by delta
    float* t1         = ws + (size_t)N * 897;
    float* delta      = t1;
    // region 3: [1281N, 2049N): mu_cat
    float* mu_cat     = ws + (size_t)N * 1281;

    float* outq  = (float*)d_out;
    float* outmu = (float*)d_out + (size_t)N * 128;

    // zero accumulators (scalar_msg | vector_msg | deg contiguous)
    hipMemsetAsync(ws, 0, (size_t)N * 513 * sizeof(float), stream);

    dim3 blk(256);
    // interaction node MLP: x = silu(q@Wi1+bi1)@Wi2+bi2
    gemm_kernel<true,  true><<<dim3((N + 63) / 64, 3), blk, 0, stream>>>(q,  Wi1, bi1, t1,   N, 128, 384);
    gemm_kernel<false, true><<<dim3((N + 63) / 64, 3), blk, 0, stream>>>(t1, Wi2, bi2, xbuf, N, 384, 384);

    deg_kernel<<<(E + 255) / 256, blk, 0, stream>>>(ei, deg, E);
    edge_kernel<<<(E + TE - 1) / TE, blk, 0, stream>>>(ei, rbf, uv, cutv, Wf1, bf1, Wf2, bf2,
                                                       xbuf, mu, scalar_msg, vector_msg, E);

    node_update_kernel<<<(N * HDIM + 255) / 256, blk, 0, stream>>>(q, mu, scalar_msg, vector_msg,
                                                                   deg, outq, outmu, N);
    // mixing
    gemm_kernel<false, false><<<dim3((3 * N + 63) / 64, 2), blk, 0, stream>>>(outmu, Wv, nullptr, mu_cat, 3 * N, 128, 256);
    si_kernel<<<(N * 256 + 255) / 256, blk, 0, stream>>>(outq, mu_cat, si, N);
    gemm_kernel<true,  true><<<dim3((N + 63) / 64, 3), blk, 0, stream>>>(si, Ws1, bs1, t2,    N, 256, 384);
    gemm_kernel<false, true><<<dim3((N + 63) / 64, 3), blk, 0, stream>>>(t2, Ws2, bs2, delta, N, 384, 384);
    final_kernel<<<(N * HDIM + 255) / 256, blk, 0, stream>>>(mu_cat, delta, outq, outmu, N);
}

// Round 2
// 1424.548 us; speedup vs baseline: 3.3067x; 3.3067x over previous
//
#include <hip/hip_runtime.h>
#include <math.h>

#define HDIM 128
#define RDIM 20
#define TE 64

__device__ __forceinline__ float silu_f(float v) { return v / (1.0f + __expf(-v)); }

// ---------------------------------------------------------------------------
// Generic tiled f32 GEMM: C[M,Nc] = act(A[M,K] @ W[K,Nc] + bias)
// block 256, BM=64, BN=128, BK=32, 4x8 micro-tile per thread.
// Requires K % 32 == 0, Nc % 128 == 0.
// ---------------------------------------------------------------------------
template<bool SILU, bool HASBIAS>
__global__ __launch_bounds__(256) void gemm_kernel(
    const float* __restrict__ A, const float* __restrict__ W,
    const float* __restrict__ bias, float* __restrict__ C,
    int M, int K, int Nc)
{
    __shared__ float As[64 * 33];
    __shared__ float Wsl[32 * 128];
    const int t = threadIdx.x;
    const int row0 = blockIdx.x * 64;
    const int col0 = blockIdx.y * 128;
    const int tj = t & 15, ti = t >> 4;
    const int j0 = tj * 8, i0 = ti * 4;
    float acc[4][8];
#pragma unroll
    for (int r = 0; r < 4; ++r)
#pragma unroll
        for (int c = 0; c < 8; ++c) acc[r][c] = 0.f;

    const int nkb = K >> 5;
    for (int kb = 0; kb < nkb; ++kb) {
#pragma unroll
        for (int v = 0; v < 2; ++v) {
            int qq = v * 256 + t;
            int i = qq >> 3;
            int kv = (qq & 7) << 2;
            int row = row0 + i;
            float4 f = make_float4(0.f, 0.f, 0.f, 0.f);
            if (row < M) f = *(const float4*)&A[(size_t)row * K + kb * 32 + kv];
            float* dst = &As[i * 33 + kv];
            dst[0] = f.x; dst[1] = f.y; dst[2] = f.z; dst[3] = f.w;
        }
#pragma unroll
        for (int v = 0; v < 4; ++v) {
            int qq = v * 256 + t;
            int kk = qq >> 5;
            int jv = (qq & 31) << 2;
            *(float4*)&Wsl[kk * 128 + jv] =
                *(const float4*)&W[(size_t)(kb * 32 + kk) * Nc + col0 + jv];
        }
        __syncthreads();
#pragma unroll
        for (int kk = 0; kk < 32; ++kk) {
            float4 w0 = *(float4*)&Wsl[kk * 128 + j0];
            float4 w1 = *(float4*)&Wsl[kk * 128 + j0 + 4];
#pragma unroll
            for (int r = 0; r < 4; ++r) {
                float a = As[(i0 + r) * 33 + kk];
                acc[r][0] += a * w0.x; acc[r][1] += a * w0.y;
                acc[r][2] += a * w0.z; acc[r][3] += a * w0.w;
                acc[r][4] += a * w1.x; acc[r][5] += a * w1.y;
                acc[r][6] += a * w1.z; acc[r][7] += a * w1.w;
            }
        }
        __syncthreads();
    }
#pragma unroll
    for (int r = 0; r < 4; ++r) {
        int row = row0 + i0 + r;
        if (row >= M) continue;
        float out[8];
#pragma unroll
        for (int c = 0; c < 8; ++c) {
            float v = acc[r][c];
            if (HASBIAS) v += bias[col0 + j0 + c];
            if (SILU) v = silu_f(v);
            out[c] = v;
        }
        float* cp = &C[(size_t)row * Nc + col0 + j0];
        *(float4*)&cp[0] = make_float4(out[0], out[1], out[2], out[3]);
        *(float4*)&cp[4] = make_float4(out[4], out[5], out[6], out[7]);
    }
}

// ---------------------------------------------------------------------------
// Counting sort of edges by target: histogram -> scan -> rank scatter
// ---------------------------------------------------------------------------
__global__ void deg_hist_kernel(const int* __restrict__ ei, int* __restrict__ deg_i, int E) {
    int e = blockIdx.x * 256 + threadIdx.x;
    if (e < E) atomicAdd(&deg_i[ei[e]], 1);
}

__global__ void scan_kernel(const int* __restrict__ deg_i, int* __restrict__ offs, int N) {
    __shared__ int s[256];
    int t = threadIdx.x;
    int chunk = (N + 255) / 256;
    int a = t * chunk, b = min(a + chunk, N);
    int sum = 0;
    for (int i = a; i < b; ++i) sum += deg_i[i];
    s[t] = sum;
    __syncthreads();
    for (int d = 1; d < 256; d <<= 1) {
        int v = (t >= d) ? s[t - d] : 0;
        __syncthreads();
        s[t] += v;
        __syncthreads();
    }
    int run = (t > 0) ? s[t - 1] : 0;
    for (int i = a; i < b; ++i) { offs[i] = run; run += deg_i[i]; }
}

__global__ void scatter_kernel(const int* __restrict__ ei, const int* __restrict__ offs,
                               int* __restrict__ counters, int* __restrict__ perm, int E) {
    int e = blockIdx.x * 256 + threadIdx.x;
    if (e < E) {
        int tg = ei[e];
        int pos = offs[tg] + atomicAdd(&counters[tg], 1);
        perm[pos] = e;
    }
}

// ---------------------------------------------------------------------------
// Fused edge kernel over TARGET-SORTED edges.
//   h = silu(rbf@Wf1+bf1) (LDS) ; F = (h@Wf2+bf2)*cutoff (3 chunks)
//   per-edge messages -> LDS plane -> segmented reduce down sorted targets:
//   interior segments = plain coalesced stores, boundary segments = atomics.
// ---------------------------------------------------------------------------
__global__ __launch_bounds__(256) void edge_kernel(
    const int* __restrict__ ei, const int* __restrict__ perm,
    const float* __restrict__ rbf,
    const float* __restrict__ uv, const float* __restrict__ cutv,
    const float* __restrict__ Wf1, const float* __restrict__ bf1,
    const float* __restrict__ Wf2, const float* __restrict__ bf2,
    const float* __restrict__ x, const float* __restrict__ mu,
    float* __restrict__ scalar_msg, float* __restrict__ vector_msg,
    int E)
{
    __shared__ float s_rbf[TE * RDIM];
    __shared__ float s_h[TE * 132];     // h values; later reduce plane #1
    __shared__ float s_w[TE * 132];     // W tiles (uses first 32*128*2); later plane #0
    __shared__ int   s_eid[TE];
    __shared__ int   s_src[TE];
    __shared__ int   s_tgt[TE];
    __shared__ float s_cut[TE];
    __shared__ float s_uv[TE * 3];

    const int t = threadIdx.x;
    const int e0 = blockIdx.x * TE;

    // ---- metadata gather (sorted order) ----
    if (t < TE) {
        int p = e0 + t;
        int e = (p < E) ? perm[p] : -1;
        s_eid[t] = e;
        s_tgt[t] = (e >= 0) ? ei[e] : -1;
        s_src[t] = (e >= 0) ? ei[(size_t)E + e] : 0;
        s_cut[t] = (e >= 0) ? cutv[e] : 0.f;
    }
    __syncthreads();
    for (int qq = t; qq < TE * 5; qq += 256) {       // rbf rows as 5x float4
        int i = qq / 5, part = qq - i * 5;
        int e = s_eid[i];
        float4 f = make_float4(0.f, 0.f, 0.f, 0.f);
        if (e >= 0) f = *(const float4*)&rbf[(size_t)e * RDIM + part * 4];
        *(float4*)&s_rbf[i * RDIM + part * 4] = f;
    }
    for (int qq = t; qq < TE * 3; qq += 256) {
        int i = qq / 3, c = qq - i * 3;
        int e = s_eid[i];
        s_uv[qq] = (e >= 0) ? uv[(size_t)e * 3 + c] : 0.f;
    }
    __syncthreads();

    // ---- h = silu(rbf @ Wf1 + bf1) ----
    for (int qq = t; qq < TE * HDIM; qq += 256) {
        int i = qq >> 7, k = qq & 127;
        float a = bf1[k];
#pragma unroll
        for (int r = 0; r < RDIM; ++r) a += s_rbf[i * RDIM + r] * Wf1[r * HDIM + k];
        s_h[i * 132 + k] = silu_f(a);
    }
    __syncthreads();

    const int tj = t & 15, ti = t >> 4;
    const int j0 = tj * 8, i0 = ti * 4;

    // ================= pass A: filter_q -> scalar messages =================
    float accq[4][8];
#pragma unroll
    for (int r = 0; r < 4; ++r)
#pragma unroll
        for (int c = 0; c < 8; ++c) accq[r][c] = 0.f;

    for (int kb = 0; kb < 4; ++kb) {
#pragma unroll
        for (int v = 0; v < 4; ++v) {
            int qq = v * 256 + t;
            int kk = qq >> 5, jv = (qq & 31) << 2;
            *(float4*)&s_w[kk * 128 + jv] =
                *(const float4*)&Wf2[(size_t)(kb * 32 + kk) * 384 + jv];
        }
        __syncthreads();
#pragma unroll
        for (int kk = 0; kk < 32; ++kk) {
            float4 w0 = *(float4*)&s_w[kk * 128 + j0];
            float4 w1 = *(float4*)&s_w[kk * 128 + j0 + 4];
            int kg = kb * 32 + kk;
#pragma unroll
            for (int r = 0; r < 4; ++r) {
                float a = s_h[(i0 + r) * 132 + kg];
                accq[r][0] += a * w0.x; accq[r][1] += a * w0.y;
                accq[r][2] += a * w0.z; accq[r][3] += a * w0.w;
                accq[r][4] += a * w1.x; accq[r][5] += a * w1.y;
                accq[r][6] += a * w1.z; accq[r][7] += a * w1.w;
            }
        }
        __syncthreads();
    }
    // per-edge scalar values -> plane (s_w, stride 132)
    {
        float bq[8];
#pragma unroll
        for (int c = 0; c < 8; ++c) bq[c] = bf2[j0 + c];
#pragma unroll
        for (int r = 0; r < 4; ++r) {
            int i = i0 + r;
            int s = s_src[i];
            float cu = s_cut[i];
            const float* xp = &x[(size_t)s * 384 + j0];
            float4 x0 = *(const float4*)&xp[0];
            float4 x1 = *(const float4*)&xp[4];
            float xv[8] = {x0.x, x0.y, x0.z, x0.w, x1.x, x1.y, x1.z, x1.w};
#pragma unroll
            for (int c = 0; c < 8; ++c)
                s_w[i * 132 + j0 + c] = (accq[r][c] + bq[c]) * cu * xv[c];
        }
    }
    __syncthreads();
    // segmented reduce (64 rows) -> scalar_msg
    if (t < 128) {
        int col = t;
        float acc = 0.f;
        int prev = s_tgt[0];
        bool first = true;
        for (int i = 0; i < TE; ++i) {
            int tg = s_tgt[i];
            if (tg != prev) {
                if (prev >= 0) {
                    float* dst = &scalar_msg[(size_t)prev * HDIM + col];
                    if (first) atomicAdd(dst, acc); else *dst = acc;
                }
                acc = 0.f; prev = tg; first = false;
            }
            acc += s_w[i * 132 + col];
        }
        if (prev >= 0) atomicAdd(&scalar_msg[(size_t)prev * HDIM + col], acc);
    }
    __syncthreads();

    // ============ pass B: filter_r & filter_mu -> vector messages ==========
    float accr[4][8], accm[4][8];
#pragma unroll
    for (int r = 0; r < 4; ++r)
#pragma unroll
        for (int c = 0; c < 8; ++c) { accr[r][c] = 0.f; accm[r][c] = 0.f; }

    for (int kb = 0; kb < 4; ++kb) {
#pragma unroll
        for (int v = 0; v < 8; ++v) {
            int qq = v * 256 + t;
            int half = qq >> 10;
            int rem = qq & 1023;
            int kk = rem >> 5, jv = (rem & 31) << 2;
            *(float4*)&s_w[half * 4096 + kk * 128 + jv] =
                *(const float4*)&Wf2[(size_t)(kb * 32 + kk) * 384 + 128 + half * 128 + jv];
        }
        __syncthreads();
#pragma unroll
        for (int kk = 0; kk < 32; ++kk) {
            float4 w0 = *(float4*)&s_w[kk * 128 + j0];
            float4 w1 = *(float4*)&s_w[kk * 128 + j0 + 4];
            float4 w2 = *(float4*)&s_w[4096 + kk * 128 + j0];
            float4 w3 = *(float4*)&s_w[4096 + kk * 128 + j0 + 4];
            int kg = kb * 32 + kk;
#pragma unroll
            for (int r = 0; r < 4; ++r) {
                float a = s_h[(i0 + r) * 132 + kg];
                accr[r][0] += a * w0.x; accr[r][1] += a * w0.y;
                accr[r][2] += a * w0.z; accr[r][3] += a * w0.w;
                accr[r][4] += a * w1.x; accr[r][5] += a * w1.y;
                accr[r][6] += a * w1.z; accr[r][7] += a * w1.w;
                accm[r][0] += a * w2.x; accm[r][1] += a * w2.y;
                accm[r][2] += a * w2.z; accm[r][3] += a * w2.w;
                accm[r][4] += a * w3.x; accm[r][5] += a * w3.y;
                accm[r][6] += a * w3.z; accm[r][7] += a * w3.w;
            }
        }
        __syncthreads();
    }

    // per-edge vr/vm (keep in registers; accr/accm die here)
    float vr[4][8], vm[4][8];
    {
        float br[8], bm[8];
#pragma unroll
        for (int c = 0; c < 8; ++c) { br[c] = bf2[128 + j0 + c]; bm[c] = bf2[256 + j0 + c]; }
#pragma unroll
        for (int r = 0; r < 4; ++r) {
            int i = i0 + r;
            int s = s_src[i];
            float cu = s_cut[i];
            const float* xb = &x[(size_t)s * 384];
            float4 a0 = *(const float4*)&xb[128 + j0];
            float4 a1 = *(const float4*)&xb[128 + j0 + 4];
            float4 b0 = *(const float4*)&xb[256 + j0];
            float4 b1 = *(const float4*)&xb[256 + j0 + 4];
            float xr[8] = {a0.x, a0.y, a0.z, a0.w, a1.x, a1.y, a1.z, a1.w};
            float xm[8] = {b0.x, b0.y, b0.z, b0.w, b1.x, b1.y, b1.z, b1.w};
#pragma unroll
            for (int c = 0; c < 8; ++c) {
                vr[r][c] = (accr[r][c] + br[c]) * cu * xr[c];
                vm[r][c] = (accm[r][c] + bm[c]) * cu * xm[c];
            }
        }
    }

    // planes 0 (s_w) and 1 (s_h): x/y components
#pragma unroll
    for (int r = 0; r < 4; ++r) {
        int i = i0 + r;
        int s = s_src[i];
        float ux = s_uv[i * 3], uyy = s_uv[i * 3 + 1];
        const float* mub = &mu[(size_t)s * 384 + j0];
        float4 m00 = *(const float4*)&mub[0];   float4 m01 = *(const float4*)&mub[4];
        float4 m10 = *(const float4*)&mub[128]; float4 m11 = *(const float4*)&mub[132];
        float mu0[8] = {m00.x, m00.y, m00.z, m00.w, m01.x, m01.y, m01.z, m01.w};
        float mu1[8] = {m10.x, m10.y, m10.z, m10.w, m11.x, m11.y, m11.z, m11.w};
#pragma unroll
        for (int c = 0; c < 8; ++c) {
            s_w[i * 132 + j0 + c] = ux  * vr[r][c] + mu0[c] * vm[r][c];
            s_h[i * 132 + j0 + c] = uyy * vr[r][c] + mu1[c] * vm[r][c];
        }
    }
    __syncthreads();
    {
        int col = t & 127, pl = t >> 7;
        const float* plane = pl ? s_h : s_w;
        float acc = 0.f;
        int prev = s_tgt[0];
        bool first = true;
        for (int i = 0; i < TE; ++i) {
            int tg = s_tgt[i];
            if (tg != prev) {
                if (prev >= 0) {
                    float* dst = &vector_msg[(size_t)prev * 384 + pl * 128 + col];
                    if (first) atomicAdd(dst, acc); else *dst = acc;
                }
                acc = 0.f; prev = tg; first = false;
            }
            acc += plane[i * 132 + col];
        }
        if (prev >= 0) atomicAdd(&vector_msg[(size_t)prev * 384 + pl * 128 + col], acc);
    }
    __syncthreads();

    // plane 2: z component
#pragma unroll
    for (int r = 0; r < 4; ++r) {
        int i = i0 + r;
        int s = s_src[i];
        float uzz = s_uv[i * 3 + 2];
        const float* mub = &mu[(size_t)s * 384 + 256 + j0];
        float4 m20 = *(const float4*)&mub[0]; float4 m21 = *(const float4*)&mub[4];
        float mu2[8] = {m20.x, m20.y, m20.z, m20.w, m21.x, m21.y, m21.z, m21.w};
#pragma unroll
        for (int c = 0; c < 8; ++c)
            s_w[i * 132 + j0 + c] = uzz * vr[r][c] + mu2[c] * vm[r][c];
    }
    __syncthreads();
    if (t < 128) {
        int col = t;
        float acc = 0.f;
        int prev = s_tgt[0];
        bool first = true;
        for (int i = 0; i < TE; ++i) {
            int tg = s_tgt[i];
            if (tg != prev) {
                if (prev >= 0) {
                    float* dst = &vector_msg[(size_t)prev * 384 + 256 + col];
                    if (first) atomicAdd(dst, acc); else *dst = acc;
                }
                acc = 0.f; prev = tg; first = false;
            }
            acc += s_w[i * 132 + col];
        }
        if (prev >= 0) atomicAdd(&vector_msg[(size_t)prev * 384 + 256 + col], acc);
    }
}

// ---------------------------------------------------------------------------
// q_new = q + scalar/deg ; mu_new = mu + vec/deg   (written into d_out)
// ---------------------------------------------------------------------------
__global__ void node_update_kernel(const float* __restrict__ q, const float* __restrict__ mu,
    const float* __restrict__ scalar_msg, const float* __restrict__ vector_msg,
    const int* __restrict__ deg_i, float* __restrict__ outq, float* __restrict__ outmu, int N)
{
    int idx = blockIdx.x * 256 + threadIdx.x;
    if (idx >= N * HDIM) return;
    int n = idx >> 7, k = idx & 127;
    float inv = 1.0f / fmaxf((float)deg_i[n], 1.0f);
    outq[idx] = q[idx] + scalar_msg[idx] * inv;
#pragma unroll
    for (int c = 0; c < 3; ++c) {
        size_t o = ((size_t)n * 3 + c) * HDIM + k;
        outmu[o] = mu[o] + vector_msg[o] * inv;
    }
}

// ---------------------------------------------------------------------------
// scalar_input = [q_new, ||mu_v||]
// ---------------------------------------------------------------------------
__global__ void si_kernel(const float* __restrict__ outq, const float* __restrict__ mu_cat,
                          float* __restrict__ si, int N)
{
    int idx = blockIdx.x * 256 + threadIdx.x;
    if (idx >= N * 256) return;
    int n = idx >> 8, j = idx & 255;
    if (j < 128) {
        si[idx] = outq[n * 128 + j];
    } else {
        int k = j - 128;
        float s2 = 1e-8f;
#pragma unroll
        for (int c = 0; c < 3; ++c) {
            float v = mu_cat[((size_t)n * 3 + c) * 256 + k];
            s2 += v * v;
        }
        si[idx] = sqrtf(s2);
    }
}

// ---------------------------------------------------------------------------
// final: q += dq + dqmu*inner ; mu += mu_w * dmu_scale
// ---------------------------------------------------------------------------
__global__ void final_kernel(const float* __restrict__ mu_cat, const float* __restrict__ delta,
                             float* __restrict__ outq, float* __restrict__ outmu, int N)
{
    int idx = blockIdx.x * 256 + threadIdx.x;
    if (idx >= N * HDIM) return;
    int n = idx >> 7, k = idx & 127;
    float inner = 0.f, mw[3];
#pragma unroll
    for (int c = 0; c < 3; ++c) {
        float mv = mu_cat[((size_t)n * 3 + c) * 256 + k];
        mw[c] = mu_cat[((size_t)n * 3 + c) * 256 + 128 + k];
        inner += mv * mw[c];
    }
    const float* dl = &delta[(size_t)n * 384];
    float dq = dl[k], dsc = dl[128 + k], dqm = dl[256 + k];
    outq[idx] += dq + dqm * inner;
#pragma unroll
    for (int c = 0; c < 3; ++c) {
        size_t o = ((size_t)n * 3 + c) * HDIM + k;
        outmu[o] += mw[c] * dsc;
    }
}

// ---------------------------------------------------------------------------
extern "C" void kernel_launch(void* const* d_in, const int* in_sizes, int n_in,
                              void* d_out, int out_size, void* d_ws, size_t ws_size,
                              hipStream_t stream)
{
    const float* q    = (const float*)d_in[0];
    const float* mu   = (const float*)d_in[1];
    const int*   ei   = (const int*)d_in[2];
    const float* rbf  = (const float*)d_in[3];
    const float* uv   = (const float*)d_in[4];
    const float* cutv = (const float*)d_in[5];
    const float* Wi1  = (const float*)d_in[6];
    const float* bi1  = (const float*)d_in[7];
    const float* Wi2  = (const float*)d_in[8];
    const float* bi2  = (const float*)d_in[9];
    const float* Wf1  = (const float*)d_in[10];
    const float* bf1  = (const float*)d_in[11];
    const float* Wf2  = (const float*)d_in[12];
    const float* bf2  = (const float*)d_in[13];
    const float* Wv   = (const float*)d_in[14];
    const float* Ws1  = (const float*)d_in[15];
    const float* bs1  = (const float*)d_in[16];
    const float* Ws2  = (const float*)d_in[17];
    const float* bs2  = (const float*)d_in[18];

    const int N = in_sizes[0] / HDIM;     // 10000
    const int E = in_sizes[2] / 2;        // 320000

    float* ws = (float*)d_ws;
    // region 0: [0, 512N): scalar_msg(128N) | vector_msg(384N); reused by t2
    float* scalar_msg = ws;
    float* vector_msg = ws + (size_t)N * 128;
    float* t2         = ws;
    // region 1: [512N, 896N): x ; reused by si
    float* xbuf       = ws + (size_t)N * 512;
    float* si         = xbuf;
    // region 2: [896N, 1280N): t1 ; reused by delta
    float* t1         = ws + (size_t)N * 896;
    float* delta      = t1;
    // region 3: [1280N, 2048N): mu_cat ; its first 3N+E ints host the sort
    //           scratch (deg_i, counters, offs, perm), dead before mu_cat is written.
    float* mu_cat     = ws + (size_t)N * 1280;
    int*   ibase      = (int*)mu_cat;
    int*   deg_i      = ibase;
    int*   counters   = ibase + N;
    int*   offs       = ibase + 2 * (size_t)N;
    int*   perm       = ibase + 3 * (size_t)N;

    float* outq  = (float*)d_out;
    float* outmu = (float*)d_out + (size_t)N * 128;

    hipMemsetAsync(ws, 0, (size_t)N * 512 * sizeof(float), stream);   // messages
    hipMemsetAsync(ibase, 0, (size_t)2 * N * sizeof(int), stream);    // deg + counters

    dim3 blk(256);
    // interaction node MLP: x = silu(q@Wi1+bi1)@Wi2+bi2
    gemm_kernel<true,  true><<<dim3((N + 63) / 64, 3), blk, 0, stream>>>(q,  Wi1, bi1, t1,   N, 128, 384);
    gemm_kernel<false, true><<<dim3((N + 63) / 64, 3), blk, 0, stream>>>(t1, Wi2, bi2, xbuf, N, 384, 384);

    // counting sort of edges by target
    deg_hist_kernel<<<(E + 255) / 256, blk, 0, stream>>>(ei, deg_i, E);
    scan_kernel<<<1, blk, 0, stream>>>(deg_i, offs, N);
    scatter_kernel<<<(E + 255) / 256, blk, 0, stream>>>(ei, offs, counters, perm, E);

    edge_kernel<<<(E + TE - 1) / TE, blk, 0, stream>>>(ei, perm, rbf, uv, cutv,
                                                       Wf1, bf1, Wf2, bf2,
                                                       xbuf, mu, scalar_msg, vector_msg, E);

    node_update_kernel<<<(N * HDIM + 255) / 256, blk, 0, stream>>>(q, mu, scalar_msg, vector_msg,
                                                                   deg_i, outq, outmu, N);
    // mixing
    gemm_kernel<false, false><<<dim3((3 * N + 63) / 64, 2), blk, 0, stream>>>(outmu, Wv, nullptr, mu_cat, 3 * N, 128, 256);
    si_kernel<<<(N * 256 + 255) / 256, blk, 0, stream>>>(outq, mu_cat, si, N);
    gemm_kernel<true,  true><<<dim3((N + 63) / 64, 3), blk, 0, stream>>>(si, Ws1, bs1, t2,    N, 256, 384);
    gemm_kernel<false, true><<<dim3((N + 63) / 64, 3), blk, 0, stream>>>(t2, Ws2, bs2, delta, N, 384, 384);
    final_kernel<<<(N * HDIM + 255) / 256, blk, 0, stream>>>(mu_cat, delta, outq, outmu, N);
}

// Round 3
// 490.958 us; speedup vs baseline: 9.5946x; 2.9016x over previous
//
#include <hip/hip_runtime.h>
#include <math.h>

#define HDIM 128
#define RDIM 20
#define TE 64
#define PSTR 132

typedef __attribute__((ext_vector_type(8))) short short8;
typedef __attribute__((ext_vector_type(4))) float f32x4;

__device__ __forceinline__ float silu_f(float v) { return v / (1.0f + __expf(-v)); }

__device__ __forceinline__ short f2b(float x) {
    unsigned u = __float_as_uint(x);
    u += 0x7fffu + ((u >> 16) & 1u);
    return (short)(u >> 16);
}

// ---------------------------------------------------------------------------
// Generic tiled f32 GEMM (node MLPs): C = act(A@W + bias)
// ---------------------------------------------------------------------------
template<bool SILU, bool HASBIAS>
__global__ __launch_bounds__(256) void gemm_kernel(
    const float* __restrict__ A, const float* __restrict__ W,
    const float* __restrict__ bias, float* __restrict__ C,
    int M, int K, int Nc)
{
    __shared__ float As[64 * 33];
    __shared__ float Wsl[32 * 128];
    const int t = threadIdx.x;
    const int row0 = blockIdx.x * 64;
    const int col0 = blockIdx.y * 128;
    const int tj = t & 15, ti = t >> 4;
    const int j0 = tj * 8, i0 = ti * 4;
    float acc[4][8];
#pragma unroll
    for (int r = 0; r < 4; ++r)
#pragma unroll
        for (int c = 0; c < 8; ++c) acc[r][c] = 0.f;

    const int nkb = K >> 5;
    for (int kb = 0; kb < nkb; ++kb) {
#pragma unroll
        for (int v = 0; v < 2; ++v) {
            int qq = v * 256 + t;
            int i = qq >> 3;
            int kv = (qq & 7) << 2;
            int row = row0 + i;
            float4 f = make_float4(0.f, 0.f, 0.f, 0.f);
            if (row < M) f = *(const float4*)&A[(size_t)row * K + kb * 32 + kv];
            float* dst = &As[i * 33 + kv];
            dst[0] = f.x; dst[1] = f.y; dst[2] = f.z; dst[3] = f.w;
        }
#pragma unroll
        for (int v = 0; v < 4; ++v) {
            int qq = v * 256 + t;
            int kk = qq >> 5;
            int jv = (qq & 31) << 2;
            *(float4*)&Wsl[kk * 128 + jv] =
                *(const float4*)&W[(size_t)(kb * 32 + kk) * Nc + col0 + jv];
        }
        __syncthreads();
#pragma unroll
        for (int kk = 0; kk < 32; ++kk) {
            float4 w0 = *(float4*)&Wsl[kk * 128 + j0];
            float4 w1 = *(float4*)&Wsl[kk * 128 + j0 + 4];
#pragma unroll
            for (int r = 0; r < 4; ++r) {
                float a = As[(i0 + r) * 33 + kk];
                acc[r][0] += a * w0.x; acc[r][1] += a * w0.y;
                acc[r][2] += a * w0.z; acc[r][3] += a * w0.w;
                acc[r][4] += a * w1.x; acc[r][5] += a * w1.y;
                acc[r][6] += a * w1.z; acc[r][7] += a * w1.w;
            }
        }
        __syncthreads();
    }
#pragma unroll
    for (int r = 0; r < 4; ++r) {
        int row = row0 + i0 + r;
        if (row >= M) continue;
        float out[8];
#pragma unroll
        for (int c = 0; c < 8; ++c) {
            float v = acc[r][c];
            if (HASBIAS) v += bias[col0 + j0 + c];
            if (SILU) v = silu_f(v);
            out[c] = v;
        }
        float* cp = &C[(size_t)row * Nc + col0 + j0];
        *(float4*)&cp[0] = make_float4(out[0], out[1], out[2], out[3]);
        *(float4*)&cp[4] = make_float4(out[4], out[5], out[6], out[7]);
    }
}

// ---------------------------------------------------------------------------
// Pack Wf1/Wf2 into MFMA B-fragment order (bf16): frag[ct][lane][j] layout.
// B-frag semantics: lane l supplies B[k=(l>>4)*8+j][col=ct*16+(l&15)].
// ---------------------------------------------------------------------------
__global__ void pack_kernel(const float* __restrict__ Wf1, const float* __restrict__ Wf2,
                            short* __restrict__ pw1, short* __restrict__ pw2)
{
    int t = blockIdx.x * 256 + threadIdx.x;
    if (t < 4096) {                       // pw1: ct(8) x lane(64) x j(8), K=32 (pad 20)
        int j = t & 7, lane = (t >> 3) & 63, ct = t >> 9;
        int k = (lane >> 4) * 8 + j;
        int col = ct * 16 + (lane & 15);
        float v = (k < RDIM) ? Wf1[k * HDIM + col] : 0.f;
        pw1[t] = f2b(v);
    }
    int u = t - 4096;                     // pw2: kb(4) x ct(24) x lane(64) x j(8)
    if (u >= 0 && u < 49152) {
        int j = u & 7, lane = (u >> 3) & 63, rest = u >> 9;
        int ct = rest % 24, kb = rest / 24;
        int k = kb * 32 + (lane >> 4) * 8 + j;
        int col = ct * 16 + (lane & 15);
        pw2[u] = f2b(Wf2[(size_t)k * 384 + col]);
    }
}

// ---------------------------------------------------------------------------
// Counting sort of edges by target
// ---------------------------------------------------------------------------
__global__ void deg_hist_kernel(const int* __restrict__ ei, int* __restrict__ deg_i, int E) {
    int e = blockIdx.x * 256 + threadIdx.x;
    if (e < E) atomicAdd(&deg_i[ei[e]], 1);
}

__global__ void scan_kernel(const int* __restrict__ deg_i, int* __restrict__ offs, int N) {
    __shared__ int s[256];
    int t = threadIdx.x;
    int chunk = (N + 255) / 256;
    int a = t * chunk, b = min(a + chunk, N);
    int sum = 0;
    for (int i = a; i < b; ++i) sum += deg_i[i];
    s[t] = sum;
    __syncthreads();
    for (int d = 1; d < 256; d <<= 1) {
        int v = (t >= d) ? s[t - d] : 0;
        __syncthreads();
        s[t] += v;
        __syncthreads();
    }
    int run = (t > 0) ? s[t - 1] : 0;
    for (int i = a; i < b; ++i) { offs[i] = run; run += deg_i[i]; }
}

__global__ void scatter_kernel(const int* __restrict__ ei, const int* __restrict__ offs,
                               int* __restrict__ counters, int* __restrict__ perm, int E) {
    int e = blockIdx.x * 256 + threadIdx.x;
    if (e < E) {
        int tg = ei[e];
        int pos = offs[tg] + atomicAdd(&counters[tg], 1);
        perm[pos] = e;
    }
}

// ---------------------------------------------------------------------------
// Segmented scan of a 64-row LDS plane down sorted targets (2 row-halves).
// ---------------------------------------------------------------------------
__device__ __forceinline__ void scan_plane(const float* __restrict__ sp,
                                           const int* __restrict__ s_tgt,
                                           float* __restrict__ dst,
                                           int rowstride, int coloff, int t)
{
    int col = t & 127;
    int r0 = (t >> 7) * 32;
    float acc = 0.f;
    int prev = s_tgt[r0];
    bool first = true;
    for (int i = r0; i < r0 + 32; ++i) {
        int tg = s_tgt[i];
        if (tg != prev) {
            if (prev >= 0) {
                float* d = dst + (size_t)prev * rowstride + coloff + col;
                if (first) atomicAdd(d, acc); else *d = acc;
            }
            acc = 0.f; prev = tg; first = false;
        }
        acc += sp[i * PSTR + col];
    }
    if (prev >= 0) atomicAdd(dst + (size_t)prev * rowstride + coloff + col, acc);
}

// ---------------------------------------------------------------------------
// Fused edge kernel (MFMA): per block = 64 target-sorted edges.
//   h = silu(rbf@Wf1+bf1)  via mfma (A=rbf frags from global, B=pw1)
//   filters plane p via mfma (A=h from LDS swizzled, B=pw2) -> LDS plane
//   -> thread-layout multiply with gathered x/mu -> segmented scan.
// ---------------------------------------------------------------------------
__global__ __launch_bounds__(256, 3) void edge_kernel(
    const int* __restrict__ ei, const int* __restrict__ perm,
    const float* __restrict__ rbf,
    const float* __restrict__ uv, const float* __restrict__ cutv,
    const short* __restrict__ pw1, const short* __restrict__ pw2,
    const float* __restrict__ bf1, const float* __restrict__ bf2,
    const float* __restrict__ x, const float* __restrict__ mu,
    float* __restrict__ scalar_msg, float* __restrict__ vector_msg,
    int E)
{
    __shared__ short s_h[64 * 128];        // bf16 h, chunk-XOR swizzled (16 KB)
    __shared__ float s_plane[64 * PSTR];   // 33 KB working plane
    __shared__ int   s_eid[TE];
    __shared__ int   s_tgt[TE];
    __shared__ int   s_src[TE];
    __shared__ float s_cut[TE];
    __shared__ float s_uv[TE * 3];

    const int t = threadIdx.x;
    const int w = t >> 6;       // wave id 0..3
    const int l = t & 63;       // lane
    const int e0 = blockIdx.x * TE;

    // ---- metadata ----
    if (t < TE) {
        int p = e0 + t;
        int e = (p < E) ? perm[p] : -1;
        s_eid[t] = e;
        s_tgt[t] = (e >= 0) ? ei[e] : -1;
        s_src[t] = (e >= 0) ? ei[(size_t)E + e] : 0;
        s_cut[t] = (e >= 0) ? cutv[e] : 0.f;
    }
    if (t >= 64 && t < 64 + TE * 3) {
        int qq = t - 64;
        int i = qq / 3, c = qq - i * 3;
        // s_eid not ready yet; do uv below after sync
        (void)i; (void)c;
    }
    __syncthreads();
    if (t < TE * 3) {
        int i = t / 3, c = t - i * 3;
        int e = s_eid[i];
        s_uv[t] = (e >= 0) ? uv[(size_t)e * 3 + c] : 0.f;
    }

    // ---- MFMA1: h = silu(rbf @ Wf1 + bf1) ----
    // A-frag: lane l -> rbf[edge = w*16+(l&15)][k=(l>>4)*8+j], padded to 32
    short8 Ar;
#pragma unroll
    for (int j = 0; j < 8; ++j) Ar[j] = 0;
    {
        int erow = w * 16 + (l & 15);
        int eidr = s_eid[erow];
        int g = l >> 4;
        if (eidr >= 0) {
            const float* rp = &rbf[(size_t)eidr * RDIM];
            if (g < 2) {
                float4 f0 = *(const float4*)&rp[g * 8];
                float4 f1 = *(const float4*)&rp[g * 8 + 4];
                Ar[0] = f2b(f0.x); Ar[1] = f2b(f0.y); Ar[2] = f2b(f0.z); Ar[3] = f2b(f0.w);
                Ar[4] = f2b(f1.x); Ar[5] = f2b(f1.y); Ar[6] = f2b(f1.z); Ar[7] = f2b(f1.w);
            } else if (g == 2) {
                float4 f0 = *(const float4*)&rp[16];
                Ar[0] = f2b(f0.x); Ar[1] = f2b(f0.y); Ar[2] = f2b(f0.z); Ar[3] = f2b(f0.w);
            }
        }
    }
    {
        f32x4 Hc[8];
#pragma unroll
        for (int ct = 0; ct < 8; ++ct) {
            f32x4 z = {0.f, 0.f, 0.f, 0.f};
            short8 Bw = *(const short8*)&pw1[(ct * 64 + l) * 8];
            Hc[ct] = __builtin_amdgcn_mfma_f32_16x16x32_bf16(Ar, Bw, z, 0, 0, 0);
        }
        // silu + bf16 + swizzled LDS write
#pragma unroll
        for (int ct = 0; ct < 8; ++ct) {
            int colbase = ct * 16 + (l & 15);
            float b1 = bf1[colbase];
#pragma unroll
            for (int reg = 0; reg < 4; ++reg) {
                int rowg = w * 16 + ((l >> 4) * 4 + reg);
                float v = silu_f(Hc[ct][reg] + b1);
                s_h[rowg * 128 + (((colbase >> 3) ^ (rowg & 7)) * 8) + (colbase & 7)] = f2b(v);
            }
        }
    }
    __syncthreads();

    const int tj = t & 15, ti = t >> 4;
    const int j0 = tj * 8, i0 = ti * 4;

    // per-plane MFMA helper (plane p: cols p*128..p*128+127; wave strip 32 cols)
    auto mfma_plane = [&](int p) {
        f32x4 C[4][2];
#pragma unroll
        for (int rt = 0; rt < 4; ++rt)
#pragma unroll
            for (int c2 = 0; c2 < 2; ++c2) C[rt][c2] = (f32x4){0.f, 0.f, 0.f, 0.f};
#pragma unroll
        for (int rt = 0; rt < 4; ++rt) {
            short8 A[4];
#pragma unroll
            for (int kb = 0; kb < 4; ++kb) {
                int row = rt * 16 + (l & 15);
                A[kb] = *(const short8*)&s_h[row * 128 + (((kb * 4 + (l >> 4)) ^ (row & 7)) * 8)];
            }
#pragma unroll
            for (int c2 = 0; c2 < 2; ++c2) {
                int ct = p * 8 + w * 2 + c2;
#pragma unroll
                for (int kb = 0; kb < 4; ++kb) {
                    short8 B = *(const short8*)&pw2[(((kb * 24 + ct) * 64 + l) * 8)];
                    C[rt][c2] = __builtin_amdgcn_mfma_f32_16x16x32_bf16(A[kb], B, C[rt][c2], 0, 0, 0);
                }
            }
        }
        // epilogue: (C + bias)*cutoff -> plane
#pragma unroll
        for (int c2 = 0; c2 < 2; ++c2) {
            int colL = w * 32 + c2 * 16 + (l & 15);
            float bv = bf2[p * 128 + colL];
#pragma unroll
            for (int rt = 0; rt < 4; ++rt) {
#pragma unroll
                for (int reg = 0; reg < 4; ++reg) {
                    int rowg = rt * 16 + ((l >> 4) * 4 + reg);
                    s_plane[rowg * PSTR + colL] = (C[rt][c2][reg] + bv) * s_cut[rowg];
                }
            }
        }
    };

    // ================= plane 0: filter_q -> scalar messages ================
    mfma_plane(0);
    __syncthreads();
    // thread-layout multiply with x_q gather (in-place)
#pragma unroll
    for (int r = 0; r < 4; ++r) {
        int i = i0 + r;
        int s = s_src[i];
        float4 f0 = *(float4*)&s_plane[i * PSTR + j0];
        float4 f1 = *(float4*)&s_plane[i * PSTR + j0 + 4];
        const float* xp = &x[(size_t)s * 384 + j0];
        float4 x0 = *(const float4*)&xp[0];
        float4 x1 = *(const float4*)&xp[4];
        f0.x *= x0.x; f0.y *= x0.y; f0.z *= x0.z; f0.w *= x0.w;
        f1.x *= x1.x; f1.y *= x1.y; f1.z *= x1.z; f1.w *= x1.w;
        *(float4*)&s_plane[i * PSTR + j0] = f0;
        *(float4*)&s_plane[i * PSTR + j0 + 4] = f1;
    }
    __syncthreads();
    scan_plane(s_plane, s_tgt, scalar_msg, HDIM, 0, t);
    __syncthreads();

    // ================= plane 1: filter_r -> vr (registers) =================
    mfma_plane(1);
    __syncthreads();
    float vr[4][8];
#pragma unroll
    for (int r = 0; r < 4; ++r) {
        int i = i0 + r;
        int s = s_src[i];
        float4 f0 = *(float4*)&s_plane[i * PSTR + j0];
        float4 f1 = *(float4*)&s_plane[i * PSTR + j0 + 4];
        const float* xp = &x[(size_t)s * 384 + 128 + j0];
        float4 x0 = *(const float4*)&xp[0];
        float4 x1 = *(const float4*)&xp[4];
        vr[r][0] = f0.x * x0.x; vr[r][1] = f0.y * x0.y; vr[r][2] = f0.z * x0.z; vr[r][3] = f0.w * x0.w;
        vr[r][4] = f1.x * x1.x; vr[r][5] = f1.y * x1.y; vr[r][6] = f1.z * x1.z; vr[r][7] = f1.w * x1.w;
    }
    __syncthreads();

    // ================= plane 2: filter_mu -> vm (registers) ================
    mfma_plane(2);
    __syncthreads();
    float vm[4][8];
#pragma unroll
    for (int r = 0; r < 4; ++r) {
        int i = i0 + r;
        int s = s_src[i];
        float4 f0 = *(float4*)&s_plane[i * PSTR + j0];
        float4 f1 = *(float4*)&s_plane[i * PSTR + j0 + 4];
        const float* xp = &x[(size_t)s * 384 + 256 + j0];
        float4 x0 = *(const float4*)&xp[0];
        float4 x1 = *(const float4*)&xp[4];
        vm[r][0] = f0.x * x0.x; vm[r][1] = f0.y * x0.y; vm[r][2] = f0.z * x0.z; vm[r][3] = f0.w * x0.w;
        vm[r][4] = f1.x * x1.x; vm[r][5] = f1.y * x1.y; vm[r][6] = f1.z * x1.z; vm[r][7] = f1.w * x1.w;
    }
    // no sync needed: each thread overwrites only its own plane region below

    // ============ vector components x/y/z: combine + scan ============
#pragma unroll
    for (int comp = 0; comp < 3; ++comp) {
        if (comp > 0) __syncthreads();   // wait for previous scan's reads
#pragma unroll
        for (int r = 0; r < 4; ++r) {
            int i = i0 + r;
            int s = s_src[i];
            float u = s_uv[i * 3 + comp];
            const float* mp = &mu[(size_t)s * 384 + comp * 128 + j0];
            float4 m0 = *(const float4*)&mp[0];
            float4 m1 = *(const float4*)&mp[4];
            float4 o0, o1;
            o0.x = u * vr[r][0] + m0.x * vm[r][0];
            o0.y = u * vr[r][1] + m0.y * vm[r][1];
            o0.z = u * vr[r][2] + m0.z * vm[r][2];
            o0.w = u * vr[r][3] + m0.w * vm[r][3];
            o1.x = u * vr[r][4] + m1.x * vm[r][4];
            o1.y = u * vr[r][5] + m1.y * vm[r][5];
            o1.z = u * vr[r][6] + m1.z * vm[r][6];
            o1.w = u * vr[r][7] + m1.w * vm[r][7];
            *(float4*)&s_plane[i * PSTR + j0] = o0;
            *(float4*)&s_plane[i * PSTR + j0 + 4] = o1;
        }
        __syncthreads();
        scan_plane(s_plane, s_tgt, vector_msg, 384, comp * 128, t);
    }
}

// ---------------------------------------------------------------------------
__global__ void node_update_kernel(const float* __restrict__ q, const float* __restrict__ mu,
    const float* __restrict__ scalar_msg, const float* __restrict__ vector_msg,
    const int* __restrict__ deg_i, float* __restrict__ outq, float* __restrict__ outmu, int N)
{
    int idx = blockIdx.x * 256 + threadIdx.x;
    if (idx >= N * HDIM) return;
    int n = idx >> 7, k = idx & 127;
    float inv = 1.0f / fmaxf((float)deg_i[n], 1.0f);
    outq[idx] = q[idx] + scalar_msg[idx] * inv;
#pragma unroll
    for (int c = 0; c < 3; ++c) {
        size_t o = ((size_t)n * 3 + c) * HDIM + k;
        outmu[o] = mu[o] + vector_msg[o] * inv;
    }
}

__global__ void si_kernel(const float* __restrict__ outq, const float* __restrict__ mu_cat,
                          float* __restrict__ si, int N)
{
    int idx = blockIdx.x * 256 + threadIdx.x;
    if (idx >= N * 256) return;
    int n = idx >> 8, j = idx & 255;
    if (j < 128) {
        si[idx] = outq[n * 128 + j];
    } else {
        int k = j - 128;
        float s2 = 1e-8f;
#pragma unroll
        for (int c = 0; c < 3; ++c) {
            float v = mu_cat[((size_t)n * 3 + c) * 256 + k];
            s2 += v * v;
        }
        si[idx] = sqrtf(s2);
    }
}

__global__ void final_kernel(const float* __restrict__ mu_cat, const float* __restrict__ delta,
                             float* __restrict__ outq, float* __restrict__ outmu, int N)
{
    int idx = blockIdx.x * 256 + threadIdx.x;
    if (idx >= N * HDIM) return;
    int n = idx >> 7, k = idx & 127;
    float inner = 0.f, mw[3];
#pragma unroll
    for (int c = 0; c < 3; ++c) {
        float mv = mu_cat[((size_t)n * 3 + c) * 256 + k];
        mw[c] = mu_cat[((size_t)n * 3 + c) * 256 + 128 + k];
        inner += mv * mw[c];
    }
    const float* dl = &delta[(size_t)n * 384];
    float dq = dl[k], dsc = dl[128 + k], dqm = dl[256 + k];
    outq[idx] += dq + dqm * inner;
#pragma unroll
    for (int c = 0; c < 3; ++c) {
        size_t o = ((size_t)n * 3 + c) * HDIM + k;
        outmu[o] += mw[c] * dsc;
    }
}

// ---------------------------------------------------------------------------
extern "C" void kernel_launch(void* const* d_in, const int* in_sizes, int n_in,
                              void* d_out, int out_size, void* d_ws, size_t ws_size,
                              hipStream_t stream)
{
    const float* q    = (const float*)d_in[0];
    const float* mu   = (const float*)d_in[1];
    const int*   ei   = (const int*)d_in[2];
    const float* rbf  = (const float*)d_in[3];
    const float* uv   = (const float*)d_in[4];
    const float* cutv = (const float*)d_in[5];
    const float* Wi1  = (const float*)d_in[6];
    const float* bi1  = (const float*)d_in[7];
    const float* Wi2  = (const float*)d_in[8];
    const float* bi2  = (const float*)d_in[9];
    const float* Wf1  = (const float*)d_in[10];
    const float* bf1  = (const float*)d_in[11];
    const float* Wf2  = (const float*)d_in[12];
    const float* bf2  = (const float*)d_in[13];
    const float* Wv   = (const float*)d_in[14];
    const float* Ws1  = (const float*)d_in[15];
    const float* bs1  = (const float*)d_in[16];
    const float* Ws2  = (const float*)d_in[17];
    const float* bs2  = (const float*)d_in[18];

    const int N = in_sizes[0] / HDIM;     // 10000
    const int E = in_sizes[2] / 2;        // 320000

    float* ws = (float*)d_ws;
    // region 0: [0, 512N): scalar_msg(128N) | vector_msg(384N); reused by t2
    float* scalar_msg = ws;
    float* vector_msg = ws + (size_t)N * 128;
    float* t2         = ws;
    // region 1: [512N, 896N): x ; reused by si
    float* xbuf       = ws + (size_t)N * 512;
    float* si         = xbuf;
    // region 2: [896N, 1280N): t1 ; reused by delta
    float* t1         = ws + (size_t)N * 896;
    float* delta      = t1;
    // region 3: [1280N, 2048N): mu_cat; first part hosts sort + pack scratch,
    //           all dead before mu_cat is written (after node_update).
    float* mu_cat     = ws + (size_t)N * 1280;
    int*   ibase      = (int*)mu_cat;
    int*   deg_i      = ibase;
    int*   counters   = ibase + N;
    int*   offs       = ibase + 2 * (size_t)N;
    int*   perm       = ibase + 3 * (size_t)N;
    short* pw1        = (short*)(perm + E);       // 4096 bf16
    short* pw2        = pw1 + 4096;               // 49152 bf16

    float* outq  = (float*)d_out;
    float* outmu = (float*)d_out + (size_t)N * 128;

    hipMemsetAsync(ws, 0, (size_t)N * 512 * sizeof(float), stream);   // messages
    hipMemsetAsync(ibase, 0, (size_t)2 * N * sizeof(int), stream);    // deg + counters

    dim3 blk(256);
    pack_kernel<<<(4096 + 49152 + 255) / 256, blk, 0, stream>>>(Wf1, Wf2, pw1, pw2);

    // interaction node MLP: x = silu(q@Wi1+bi1)@Wi2+bi2
    gemm_kernel<true,  true><<<dim3((N + 63) / 64, 3), blk, 0, stream>>>(q,  Wi1, bi1, t1,   N, 128, 384);
    gemm_kernel<false, true><<<dim3((N + 63) / 64, 3), blk, 0, stream>>>(t1, Wi2, bi2, xbuf, N, 384, 384);

    // counting sort of edges by target
    deg_hist_kernel<<<(E + 255) / 256, blk, 0, stream>>>(ei, deg_i, E);
    scan_kernel<<<1, blk, 0, stream>>>(deg_i, offs, N);
    scatter_kernel<<<(E + 255) / 256, blk, 0, stream>>>(ei, offs, counters, perm, E);

    edge_kernel<<<(E + TE - 1) / TE, blk, 0, stream>>>(ei, perm, rbf, uv, cutv,
                                                       pw1, pw2, bf1, bf2,
                                                       xbuf, mu, scalar_msg, vector_msg, E);

    node_update_kernel<<<(N * HDIM + 255) / 256, blk, 0, stream>>>(q, mu, scalar_msg, vector_msg,
                                                                   deg_i, outq, outmu, N);
    // mixing
    gemm_kernel<false, false><<<dim3((3 * N + 63) / 64, 2), blk, 0, stream>>>(outmu, Wv, nullptr, mu_cat, 3 * N, 128, 256);
    si_kernel<<<(N * 256 + 255) / 256, blk, 0, stream>>>(outq, mu_cat, si, N);
    gemm_kernel<true,  true><<<dim3((N + 63) / 64, 3), blk, 0, stream>>>(si, Ws1, bs1, t2,    N, 256, 384);
    gemm_kernel<false, true><<<dim3((N + 63) / 64, 3), blk, 0, stream>>>(t2, Ws2, bs2, delta, N, 384, 384);
    final_kernel<<<(N * HDIM + 255) / 256, blk, 0, stream>>>(mu_cat, delta, outq, outmu, N);
}

// Round 4
// 396.234 us; speedup vs baseline: 11.8883x; 1.2391x over previous
//
#include <hip/hip_runtime.h>
#include <math.h>

#define HDIM 128
#define RDIM 20
#define TE 64
#define PSH 136          // bf16 plane stride (shorts), 272 B rows, 16B-aligned

typedef __attribute__((ext_vector_type(8))) short short8;
typedef __attribute__((ext_vector_type(4))) float f32x4;

__device__ __forceinline__ float silu_f(float v) { return v / (1.0f + __expf(-v)); }

__device__ __forceinline__ short f2b(float x) {
    unsigned u = __float_as_uint(x);
    u += 0x7fffu + ((u >> 16) & 1u);
    return (short)(u >> 16);
}
__device__ __forceinline__ float b2f(short s) {
    return __uint_as_float(((unsigned)(unsigned short)s) << 16);
}

// ---------------------------------------------------------------------------
// Pack ALL weights into MFMA B-fragment bf16 order.
// B-frag: lane l supplies B[k = kb*32 + (l>>4)*8 + j][col = ct*16 + (l&15)].
// Layout: pk[off + ((kb*nct + ct)*64 + lane)*8 + j]
// Segments: pw1(Wf1,128,pad K20->32) | pw2(Wf2,384) | Wi1(384) | Wi2(384)
//           | Wv(256) | Ws1(384) | Ws2(384)
// ---------------------------------------------------------------------------
#define OFF_PW1   0
#define OFF_PW2   4096
#define OFF_PWI1  53248
#define OFF_PWI2  102400
#define OFF_PWV   249856
#define OFF_PWS1  282624
#define OFF_PWS2  380928
#define PK_TOTAL  528384

__global__ void pack_all_kernel(const float* __restrict__ Wf1, const float* __restrict__ Wf2,
                                const float* __restrict__ Wi1, const float* __restrict__ Wi2,
                                const float* __restrict__ Wv,  const float* __restrict__ Ws1,
                                const float* __restrict__ Ws2, short* __restrict__ pk)
{
    int t = blockIdx.x * 256 + threadIdx.x;
    if (t >= PK_TOTAL) return;
    const float* W; int Nc; int u; bool pad20 = false;
    if      (t < OFF_PW2)  { W = Wf1; Nc = 128; u = t;            pad20 = true; }
    else if (t < OFF_PWI1) { W = Wf2; Nc = 384; u = t - OFF_PW2;  }
    else if (t < OFF_PWI2) { W = Wi1; Nc = 384; u = t - OFF_PWI1; }
    else if (t < OFF_PWV)  { W = Wi2; Nc = 384; u = t - OFF_PWI2; }
    else if (t < OFF_PWS1) { W = Wv;  Nc = 256; u = t - OFF_PWV;  }
    else if (t < OFF_PWS2) { W = Ws1; Nc = 384; u = t - OFF_PWS1; }
    else                   { W = Ws2; Nc = 384; u = t - OFF_PWS2; }
    int j = u & 7, lane = (u >> 3) & 63, rest = u >> 9;
    int nct = Nc >> 4, ct = rest % nct, kb = rest / nct;
    int k = kb * 32 + ((lane >> 4) << 3) + j;
    int col = ct * 16 + (lane & 15);
    float v = (pad20 && k >= RDIM) ? 0.f : W[(size_t)k * Nc + col];
    pk[t] = f2b(v);
}

// ---------------------------------------------------------------------------
// Generic MFMA GEMM: C[M,Nc] = act(A[M,K] @ W + bias), W pre-packed bf16.
// block 256 (4 waves), tile 64x128; wave w covers cols w*32..w*32+31.
// ---------------------------------------------------------------------------
template<bool SILU, bool HASBIAS, bool OUTBF16>
__global__ __launch_bounds__(256) void gemm_mfma(
    const float* __restrict__ A, const short* __restrict__ pw,
    const float* __restrict__ bias, void* __restrict__ Cv,
    int M, int K, int Nc)
{
    __shared__ float As[64 * 36];
    const int t = threadIdx.x, w = t >> 6, l = t & 63;
    const int lr = l & 15, lg = l >> 4;
    const int row0 = blockIdx.x * 64;
    const int colb = blockIdx.y;
    const int nct = Nc >> 4;
    f32x4 acc[4][2];
#pragma unroll
    for (int rt = 0; rt < 4; ++rt)
#pragma unroll
        for (int c2 = 0; c2 < 2; ++c2) acc[rt][c2] = (f32x4){0.f, 0.f, 0.f, 0.f};

    const int nkb = K >> 5;
    for (int kb = 0; kb < nkb; ++kb) {
#pragma unroll
        for (int v = 0; v < 2; ++v) {
            int qq = v * 256 + t;
            int i = qq >> 3, kv = (qq & 7) << 2;
            int row = row0 + i;
            float4 f = make_float4(0.f, 0.f, 0.f, 0.f);
            if (row < M) f = *(const float4*)&A[(size_t)row * K + kb * 32 + kv];
            *(float4*)&As[i * 36 + kv] = f;
        }
        __syncthreads();
        short8 a[4];
#pragma unroll
        for (int rt = 0; rt < 4; ++rt) {
            const float* ap = &As[(rt * 16 + lr) * 36 + lg * 8];
            float4 f0 = *(const float4*)&ap[0];
            float4 f1 = *(const float4*)&ap[4];
            short8 s;
            s[0] = f2b(f0.x); s[1] = f2b(f0.y); s[2] = f2b(f0.z); s[3] = f2b(f0.w);
            s[4] = f2b(f1.x); s[5] = f2b(f1.y); s[6] = f2b(f1.z); s[7] = f2b(f1.w);
            a[rt] = s;
        }
#pragma unroll
        for (int c2 = 0; c2 < 2; ++c2) {
            int ct = colb * 8 + w * 2 + c2;
            short8 B = *(const short8*)&pw[((size_t)(kb * nct + ct) * 64 + l) * 8];
#pragma unroll
            for (int rt = 0; rt < 4; ++rt)
                acc[rt][c2] = __builtin_amdgcn_mfma_f32_16x16x32_bf16(a[rt], B, acc[rt][c2], 0, 0, 0);
        }
        __syncthreads();
    }
#pragma unroll
    for (int c2 = 0; c2 < 2; ++c2) {
        int col = colb * 128 + w * 32 + c2 * 16 + lr;
        float bv = HASBIAS ? bias[col] : 0.f;
#pragma unroll
        for (int rt = 0; rt < 4; ++rt) {
            int rowb = row0 + rt * 16 + lg * 4;
#pragma unroll
            for (int reg = 0; reg < 4; ++reg) {
                int rr = rowb + reg;
                if (rr >= M) continue;
                float v = acc[rt][c2][reg] + bv;
                if (SILU) v = silu_f(v);
                if (OUTBF16) ((short*)Cv)[(size_t)rr * Nc + col] = f2b(v);
                else         ((float*)Cv)[(size_t)rr * Nc + col] = v;
            }
        }
    }
}

// ---------------------------------------------------------------------------
// Counting sort of edges by target
// ---------------------------------------------------------------------------
__global__ void deg_hist_kernel(const int* __restrict__ ei, int* __restrict__ deg_i, int E) {
    int e = blockIdx.x * 256 + threadIdx.x;
    if (e < E) atomicAdd(&deg_i[ei[e]], 1);
}

__global__ void scan_kernel(const int* __restrict__ deg_i, int* __restrict__ offs, int N) {
    __shared__ int s[256];
    int t = threadIdx.x;
    int chunk = (N + 255) / 256;
    int a = t * chunk, b = min(a + chunk, N);
    int sum = 0;
    for (int i = a; i < b; ++i) sum += deg_i[i];
    s[t] = sum;
    __syncthreads();
    for (int d = 1; d < 256; d <<= 1) {
        int v = (t >= d) ? s[t - d] : 0;
        __syncthreads();
        s[t] += v;
        __syncthreads();
    }
    int run = (t > 0) ? s[t - 1] : 0;
    for (int i = a; i < b; ++i) { offs[i] = run; run += deg_i[i]; }
}

__global__ void scatter_kernel(const int* __restrict__ ei, const int* __restrict__ offs,
                               int* __restrict__ counters, int* __restrict__ perm, int E) {
    int e = blockIdx.x * 256 + threadIdx.x;
    if (e < E) {
        int tg = ei[e];
        int pos = offs[tg] + atomicAdd(&counters[tg], 1);
        perm[pos] = e;
    }
}

// ---------------------------------------------------------------------------
// Segmented scan of a 64-row bf16 LDS plane down sorted targets (2 halves).
// ---------------------------------------------------------------------------
__device__ __forceinline__ void scan_plane(const short* __restrict__ sp,
                                           const int* __restrict__ s_tgt,
                                           float* __restrict__ dst,
                                           int rowstride, int coloff, int t)
{
    int col = t & 127;
    int r0 = (t >> 7) * 32;
    float acc = 0.f;
    int prev = s_tgt[r0];
    bool first = true;
    for (int i = r0; i < r0 + 32; ++i) {
        int tg = s_tgt[i];
        if (tg != prev) {
            if (prev >= 0) {
                float* d = dst + (size_t)prev * rowstride + coloff + col;
                if (first) atomicAdd(d, acc); else *d = acc;
            }
            acc = 0.f; prev = tg; first = false;
        }
        acc += b2f(sp[i * PSH + col]);
    }
    if (prev >= 0) atomicAdd(dst + (size_t)prev * rowstride + coloff + col, acc);
}

// ---------------------------------------------------------------------------
// Fused edge kernel (MFMA) over target-sorted edges; bf16 working plane.
// ---------------------------------------------------------------------------
__global__ __launch_bounds__(256, 4) void edge_kernel(
    const int* __restrict__ ei, const int* __restrict__ perm,
    const float* __restrict__ rbf,
    const float* __restrict__ uv, const float* __restrict__ cutv,
    const short* __restrict__ pw1, const short* __restrict__ pw2,
    const float* __restrict__ bf1, const float* __restrict__ bf2,
    const float* __restrict__ x, const float* __restrict__ mu,
    float* __restrict__ scalar_msg, float* __restrict__ vector_msg,
    int E)
{
    __shared__ __align__(16) short s_h[64 * 128];      // bf16 h, XOR-swizzled
    __shared__ __align__(16) short s_plane[64 * PSH];  // bf16 plane (17.4 KB)
    __shared__ int   s_eid[TE];
    __shared__ int   s_tgt[TE];
    __shared__ int   s_src[TE];
    __shared__ float s_cut[TE];
    __shared__ float s_uv[TE * 3];

    const int t = threadIdx.x;
    const int w = t >> 6;
    const int l = t & 63;
    const int e0 = blockIdx.x * TE;

    // ---- metadata ----
    if (t < TE) {
        int p = e0 + t;
        int e = (p < E) ? perm[p] : -1;
        s_eid[t] = e;
        s_tgt[t] = (e >= 0) ? ei[e] : -1;
        s_src[t] = (e >= 0) ? ei[(size_t)E + e] : 0;
        s_cut[t] = (e >= 0) ? cutv[e] : 0.f;
    }
    __syncthreads();
    if (t < TE * 3) {
        int i = t / 3, c = t - i * 3;
        int e = s_eid[i];
        s_uv[t] = (e >= 0) ? uv[(size_t)e * 3 + c] : 0.f;
    }

    // ---- MFMA1: h = silu(rbf @ Wf1 + bf1) ----
    short8 Ar;
#pragma unroll
    for (int j = 0; j < 8; ++j) Ar[j] = 0;
    {
        int erow = w * 16 + (l & 15);
        int eidr = s_eid[erow];
        int g = l >> 4;
        if (eidr >= 0) {
            const float* rp = &rbf[(size_t)eidr * RDIM];
            if (g < 2) {
                float4 f0 = *(const float4*)&rp[g * 8];
                float4 f1 = *(const float4*)&rp[g * 8 + 4];
                Ar[0] = f2b(f0.x); Ar[1] = f2b(f0.y); Ar[2] = f2b(f0.z); Ar[3] = f2b(f0.w);
                Ar[4] = f2b(f1.x); Ar[5] = f2b(f1.y); Ar[6] = f2b(f1.z); Ar[7] = f2b(f1.w);
            } else if (g == 2) {
                float4 f0 = *(const float4*)&rp[16];
                Ar[0] = f2b(f0.x); Ar[1] = f2b(f0.y); Ar[2] = f2b(f0.z); Ar[3] = f2b(f0.w);
            }
        }
    }
    {
        f32x4 Hc[8];
#pragma unroll
        for (int ct = 0; ct < 8; ++ct) {
            f32x4 z = {0.f, 0.f, 0.f, 0.f};
            short8 Bw = *(const short8*)&pw1[(ct * 64 + l) * 8];
            Hc[ct] = __builtin_amdgcn_mfma_f32_16x16x32_bf16(Ar, Bw, z, 0, 0, 0);
        }
#pragma unroll
        for (int ct = 0; ct < 8; ++ct) {
            int colbase = ct * 16 + (l & 15);
            float b1 = bf1[colbase];
#pragma unroll
            for (int reg = 0; reg < 4; ++reg) {
                int rowg = w * 16 + ((l >> 4) * 4 + reg);
                float v = silu_f(Hc[ct][reg] + b1);
                s_h[rowg * 128 + (((colbase >> 3) ^ (rowg & 7)) * 8) + (colbase & 7)] = f2b(v);
            }
        }
    }
    __syncthreads();

    const int tj = t & 15, ti = t >> 4;
    const int j0 = tj * 8, i0 = ti * 4;

    // per-plane MFMA: plane p cols p*128..+127; wave strip 32 cols
    auto mfma_plane = [&](int p) {
        f32x4 C[4][2];
#pragma unroll
        for (int rt = 0; rt < 4; ++rt)
#pragma unroll
            for (int c2 = 0; c2 < 2; ++c2) C[rt][c2] = (f32x4){0.f, 0.f, 0.f, 0.f};
#pragma unroll
        for (int rt = 0; rt < 4; ++rt) {
            short8 A[4];
#pragma unroll
            for (int kb = 0; kb < 4; ++kb) {
                int row = rt * 16 + (l & 15);
                A[kb] = *(const short8*)&s_h[row * 128 + (((kb * 4 + (l >> 4)) ^ (row & 7)) * 8)];
            }
#pragma unroll
            for (int c2 = 0; c2 < 2; ++c2) {
                int ct = p * 8 + w * 2 + c2;
#pragma unroll
                for (int kb = 0; kb < 4; ++kb) {
                    short8 B = *(const short8*)&pw2[(((kb * 24 + ct) * 64 + l) * 8)];
                    C[rt][c2] = __builtin_amdgcn_mfma_f32_16x16x32_bf16(A[kb], B, C[rt][c2], 0, 0, 0);
                }
            }
        }
#pragma unroll
        for (int c2 = 0; c2 < 2; ++c2) {
            int colL = w * 32 + c2 * 16 + (l & 15);
            float bv = bf2[p * 128 + colL];
#pragma unroll
            for (int rt = 0; rt < 4; ++rt) {
#pragma unroll
                for (int reg = 0; reg < 4; ++reg) {
                    int rowg = rt * 16 + ((l >> 4) * 4 + reg);
                    s_plane[rowg * PSH + colL] = f2b((C[rt][c2][reg] + bv) * s_cut[rowg]);
                }
            }
        }
    };

    // ================= plane 0: filter_q -> scalar messages ================
    mfma_plane(0);
    __syncthreads();
#pragma unroll
    for (int r = 0; r < 4; ++r) {
        int i = i0 + r;
        int s = s_src[i];
        short8 pv = *(short8*)&s_plane[i * PSH + j0];
        const float* xp = &x[(size_t)s * 384 + j0];
        float4 x0 = *(const float4*)&xp[0];
        float4 x1 = *(const float4*)&xp[4];
        float xv[8] = {x0.x, x0.y, x0.z, x0.w, x1.x, x1.y, x1.z, x1.w};
        short8 o;
#pragma unroll
        for (int c = 0; c < 8; ++c) o[c] = f2b(b2f(pv[c]) * xv[c]);
        *(short8*)&s_plane[i * PSH + j0] = o;
    }
    __syncthreads();
    scan_plane(s_plane, s_tgt, scalar_msg, HDIM, 0, t);
    __syncthreads();

    // ================= plane 1: filter_r -> vr =================
    mfma_plane(1);
    __syncthreads();
    float vr[4][8];
#pragma unroll
    for (int r = 0; r < 4; ++r) {
        int i = i0 + r;
        int s = s_src[i];
        short8 pv = *(short8*)&s_plane[i * PSH + j0];
        const float* xp = &x[(size_t)s * 384 + 128 + j0];
        float4 x0 = *(const float4*)&xp[0];
        float4 x1 = *(const float4*)&xp[4];
        float xv[8] = {x0.x, x0.y, x0.z, x0.w, x1.x, x1.y, x1.z, x1.w};
#pragma unroll
        for (int c = 0; c < 8; ++c) vr[r][c] = b2f(pv[c]) * xv[c];
    }
    __syncthreads();

    // ================= plane 2: filter_mu -> vm =================
    mfma_plane(2);
    __syncthreads();
    float vm[4][8];
#pragma unroll
    for (int r = 0; r < 4; ++r) {
        int i = i0 + r;
        int s = s_src[i];
        short8 pv = *(short8*)&s_plane[i * PSH + j0];
        const float* xp = &x[(size_t)s * 384 + 256 + j0];
        float4 x0 = *(const float4*)&xp[0];
        float4 x1 = *(const float4*)&xp[4];
        float xv[8] = {x0.x, x0.y, x0.z, x0.w, x1.x, x1.y, x1.z, x1.w};
#pragma unroll
        for (int c = 0; c < 8; ++c) vm[r][c] = b2f(pv[c]) * xv[c];
    }

    // ============ vector components x/y/z: combine + scan ============
#pragma unroll
    for (int comp = 0; comp < 3; ++comp) {
        if (comp > 0) __syncthreads();
#pragma unroll
        for (int r = 0; r < 4; ++r) {
            int i = i0 + r;
            int s = s_src[i];
            float u = s_uv[i * 3 + comp];
            const float* mp = &mu[(size_t)s * 384 + comp * 128 + j0];
            float4 m0 = *(const float4*)&mp[0];
            float4 m1 = *(const float4*)&mp[4];
            float mv[8] = {m0.x, m0.y, m0.z, m0.w, m1.x, m1.y, m1.z, m1.w};
            short8 o;
#pragma unroll
            for (int c = 0; c < 8; ++c) o[c] = f2b(u * vr[r][c] + mv[c] * vm[r][c]);
            *(short8*)&s_plane[i * PSH + j0] = o;
        }
        __syncthreads();
        scan_plane(s_plane, s_tgt, vector_msg, 384, comp * 128, t);
    }
}

// ---------------------------------------------------------------------------
__global__ void node_update_kernel(const float* __restrict__ q, const float* __restrict__ mu,
    const float* __restrict__ scalar_msg, const float* __restrict__ vector_msg,
    const int* __restrict__ deg_i, float* __restrict__ outq, float* __restrict__ outmu, int N)
{
    int idx = blockIdx.x * 256 + threadIdx.x;
    if (idx >= N * HDIM) return;
    int n = idx >> 7, k = idx & 127;
    float inv = 1.0f / fmaxf((float)deg_i[n], 1.0f);
    outq[idx] = q[idx] + scalar_msg[idx] * inv;
#pragma unroll
    for (int c = 0; c < 3; ++c) {
        size_t o = ((size_t)n * 3 + c) * HDIM + k;
        outmu[o] = mu[o] + vector_msg[o] * inv;
    }
}

__global__ void si_kernel(const float* __restrict__ outq, const short* __restrict__ mu_cat,
                          float* __restrict__ si, int N)
{
    int idx = blockIdx.x * 256 + threadIdx.x;
    if (idx >= N * 256) return;
    int n = idx >> 8, j = idx & 255;
    if (j < 128) {
        si[idx] = outq[n * 128 + j];
    } else {
        int k = j - 128;
        float s2 = 1e-8f;
#pragma unroll
        for (int c = 0; c < 3; ++c) {
            float v = b2f(mu_cat[((size_t)n * 3 + c) * 256 + k]);
            s2 += v * v;
        }
        si[idx] = sqrtf(s2);
    }
}

__global__ void final_kernel(const short* __restrict__ mu_cat, const float* __restrict__ delta,
                             float* __restrict__ outq, float* __restrict__ outmu, int N)
{
    int idx = blockIdx.x * 256 + threadIdx.x;
    if (idx >= N * HDIM) return;
    int n = idx >> 7, k = idx & 127;
    float inner = 0.f, mw[3];
#pragma unroll
    for (int c = 0; c < 3; ++c) {
        float mv = b2f(mu_cat[((size_t)n * 3 + c) * 256 + k]);
        mw[c] = b2f(mu_cat[((size_t)n * 3 + c) * 256 + 128 + k]);
        inner += mv * mw[c];
    }
    const float* dl = &delta[(size_t)n * 384];
    float dq = dl[k], dsc = dl[128 + k], dqm = dl[256 + k];
    outq[idx] += dq + dqm * inner;
#pragma unroll
    for (int c = 0; c < 3; ++c) {
        size_t o = ((size_t)n * 3 + c) * HDIM + k;
        outmu[o] += mw[c] * dsc;
    }
}

// ---------------------------------------------------------------------------
extern "C" void kernel_launch(void* const* d_in, const int* in_sizes, int n_in,
                              void* d_out, int out_size, void* d_ws, size_t ws_size,
                              hipStream_t stream)
{
    const float* q    = (const float*)d_in[0];
    const float* mu   = (const float*)d_in[1];
    const int*   ei   = (const int*)d_in[2];
    const float* rbf  = (const float*)d_in[3];
    const float* uv   = (const float*)d_in[4];
    const float* cutv = (const float*)d_in[5];
    const float* Wi1  = (const float*)d_in[6];
    const float* bi1  = (const float*)d_in[7];
    const float* Wi2  = (const float*)d_in[8];
    const float* bi2  = (const float*)d_in[9];
    const float* Wf1  = (const float*)d_in[10];
    const float* bf1  = (const float*)d_in[11];
    const float* Wf2  = (const float*)d_in[12];
    const float* bf2  = (const float*)d_in[13];
    const float* Wv   = (const float*)d_in[14];
    const float* Ws1  = (const float*)d_in[15];
    const float* bs1  = (const float*)d_in[16];
    const float* Ws2  = (const float*)d_in[17];
    const float* bs2  = (const float*)d_in[18];

    const int N = in_sizes[0] / HDIM;     // 10000
    const int E = in_sizes[2] / 2;        // 320000

    float* ws = (float*)d_ws;
    // R0 [0,512N): scalar_msg(128N) | vector_msg(384N); later t2 (384N)
    float* scalar_msg = ws;
    float* vector_msg = ws + (size_t)N * 128;
    float* t2         = ws;
    // R1 [512N,896N): xbuf; later si (256N)
    float* xbuf       = ws + (size_t)N * 512;
    float* si         = xbuf;
    // R2 [896N,1280N): t1; later delta
    float* t1         = ws + (size_t)N * 896;
    float* delta      = t1;
    // R3 [1280N,1664N) floats = mu_cat bf16 [3N,256]
    short* mu_cat     = (short*)(ws + (size_t)N * 1280);
    // R4 [1664N,2048N): sort scratch + packed weights (live whole call)
    int*   ibase      = (int*)(ws + (size_t)N * 1664);
    int*   deg_i      = ibase;
    int*   counters   = ibase + N;
    int*   offs       = ibase + 2 * (size_t)N;
    int*   perm       = ibase + 3 * (size_t)N;
    short* pk         = (short*)(perm + E);       // 528384 bf16
    short* pw1        = pk + OFF_PW1;
    short* pw2        = pk + OFF_PW2;

    float* outq  = (float*)d_out;
    float* outmu = (float*)d_out + (size_t)N * 128;

    hipMemsetAsync(ws, 0, (size_t)N * 512 * sizeof(float), stream);   // messages
    hipMemsetAsync(ibase, 0, (size_t)2 * N * sizeof(int), stream);    // deg + counters

    dim3 blk(256);
    pack_all_kernel<<<(PK_TOTAL + 255) / 256, blk, 0, stream>>>(Wf1, Wf2, Wi1, Wi2, Wv, Ws1, Ws2, pk);

    // interaction node MLP: x = silu(q@Wi1+bi1)@Wi2+bi2
    gemm_mfma<true,  true, false><<<dim3((N + 63) / 64, 3), blk, 0, stream>>>(q,  pk + OFF_PWI1, bi1, t1,   N, 128, 384);
    gemm_mfma<false, true, false><<<dim3((N + 63) / 64, 3), blk, 0, stream>>>(t1, pk + OFF_PWI2, bi2, xbuf, N, 384, 384);

    // counting sort of edges by target
    deg_hist_kernel<<<(E + 255) / 256, blk, 0, stream>>>(ei, deg_i, E);
    scan_kernel<<<1, blk, 0, stream>>>(deg_i, offs, N);
    scatter_kernel<<<(E + 255) / 256, blk, 0, stream>>>(ei, offs, counters, perm, E);

    edge_kernel<<<(E + TE - 1) / TE, blk, 0, stream>>>(ei, perm, rbf, uv, cutv,
                                                       pw1, pw2, bf1, bf2,
                                                       xbuf, mu, scalar_msg, vector_msg, E);

    node_update_kernel<<<(N * HDIM + 255) / 256, blk, 0, stream>>>(q, mu, scalar_msg, vector_msg,
                                                                   deg_i, outq, outmu, N);
    // mixing
    gemm_mfma<false, false, true><<<dim3((3 * N + 63) / 64, 2), blk, 0, stream>>>(outmu, pk + OFF_PWV, nullptr, mu_cat, 3 * N, 128, 256);
    si_kernel<<<(N * 256 + 255) / 256, blk, 0, stream>>>(outq, mu_cat, si, N);
    gemm_mfma<true,  true, false><<<dim3((N + 63) / 64, 3), blk, 0, stream>>>(si, pk + OFF_PWS1, bs1, t2,    N, 256, 384);
    gemm_mfma<false, true, false><<<dim3((N + 63) / 64, 3), blk, 0, stream>>>(t2, pk + OFF_PWS2, bs2, delta, N, 384, 384);
    final_kernel<<<(N * HDIM + 255) / 256, blk, 0, stream>>>(mu_cat, delta, outq, outmu, N);
}

// Round 5
// 344.235 us; speedup vs baseline: 13.6841x; 1.1511x over previous
//
#include <hip/hip_runtime.h>
#include <math.h>

#define HDIM 128
#define RDIM 20
#define TE 64
#define PSH 136          // bf16 plane stride (shorts), 272 B rows, 16B-aligned

typedef __attribute__((ext_vector_type(8))) short short8;
typedef __attribute__((ext_vector_type(4))) float f32x4;

__device__ __forceinline__ float silu_f(float v) { return v / (1.0f + __expf(-v)); }

__device__ __forceinline__ short f2b(float x) {
    unsigned u = __float_as_uint(x);
    u += 0x7fffu + ((u >> 16) & 1u);
    return (short)(u >> 16);
}
__device__ __forceinline__ float b2f(short s) {
    return __uint_as_float(((unsigned)(unsigned short)s) << 16);
}

// ---------------------------------------------------------------------------
// Packed-weight segment offsets (bf16 elements)
// B-frag: lane l supplies B[k = kb*32 + (l>>4)*8 + j][col = ct*16 + (l&15)].
// ---------------------------------------------------------------------------
#define OFF_PW1   0
#define OFF_PW2   4096
#define OFF_PWI1  53248
#define OFF_PWI2  102400
#define OFF_PWV   249856
#define OFF_PWS1  282624
#define OFF_PWS2  380928
#define PK_TOTAL  528384

// prep: pack all weights + convert q, mu to bf16
__global__ void prep_kernel(const float* __restrict__ Wf1, const float* __restrict__ Wf2,
                            const float* __restrict__ Wi1, const float* __restrict__ Wi2,
                            const float* __restrict__ Wv,  const float* __restrict__ Ws1,
                            const float* __restrict__ Ws2, short* __restrict__ pk,
                            const float* __restrict__ q, const float* __restrict__ mu,
                            short* __restrict__ q_b, short* __restrict__ mu_b, int N)
{
    int t = blockIdx.x * 256 + threadIdx.x;
    if (t < PK_TOTAL) {
        const float* W; int Nc; int u; bool pad20 = false;
        if      (t < OFF_PW2)  { W = Wf1; Nc = 128; u = t;            pad20 = true; }
        else if (t < OFF_PWI1) { W = Wf2; Nc = 384; u = t - OFF_PW2;  }
        else if (t < OFF_PWI2) { W = Wi1; Nc = 384; u = t - OFF_PWI1; }
        else if (t < OFF_PWV)  { W = Wi2; Nc = 384; u = t - OFF_PWI2; }
        else if (t < OFF_PWS1) { W = Wv;  Nc = 256; u = t - OFF_PWV;  }
        else if (t < OFF_PWS2) { W = Ws1; Nc = 384; u = t - OFF_PWS1; }
        else                   { W = Ws2; Nc = 384; u = t - OFF_PWS2; }
        int j = u & 7, lane = (u >> 3) & 63, rest = u >> 9;
        int nct = Nc >> 4, ct = rest % nct, kb = rest / nct;
        int k = kb * 32 + ((lane >> 4) << 3) + j;
        int col = ct * 16 + (lane & 15);
        float v = (pad20 && k >= RDIM) ? 0.f : W[(size_t)k * Nc + col];
        pk[t] = f2b(v);
        return;
    }
    int u = t - PK_TOTAL;
    if (u < N * 128) { q_b[u] = f2b(q[u]); return; }
    u -= N * 128;
    if (u < N * 384) mu_b[u] = f2b(mu[u]);
}

// ---------------------------------------------------------------------------
// MFMA GEMM, bf16 A (pre-converted), pre-packed bf16 W.
// block 256 (4 waves), tile 64x128; wave w covers cols w*32..w*32+31.
// ---------------------------------------------------------------------------
template<bool SILU, bool HASBIAS, bool OUTBF16>
__global__ __launch_bounds__(256) void gemm_mfma(
    const short* __restrict__ A, const short* __restrict__ pw,
    const float* __restrict__ bias, void* __restrict__ Cv,
    int M, int K, int Nc)
{
    __shared__ short As[64 * 32];   // 4 KB, 16B chunks XOR-swizzled by row&3
    const int t = threadIdx.x, w = t >> 6, l = t & 63;
    const int lr = l & 15, lg = l >> 4;
    const int row0 = blockIdx.x * 64;
    const int colb = blockIdx.y;
    const int nct = Nc >> 4;
    f32x4 acc[4][2];
#pragma unroll
    for (int rt = 0; rt < 4; ++rt)
#pragma unroll
        for (int c2 = 0; c2 < 2; ++c2) acc[rt][c2] = (f32x4){0.f, 0.f, 0.f, 0.f};

    const int nkb = K >> 5;
    for (int kb = 0; kb < nkb; ++kb) {
        {
            int i = t >> 2, ch = t & 3;
            int row = row0 + i;
            short8 v = {0, 0, 0, 0, 0, 0, 0, 0};
            if (row < M) v = *(const short8*)&A[(size_t)row * K + kb * 32 + ch * 8];
            *(short8*)&As[i * 32 + ((ch ^ (i & 3)) * 8)] = v;
        }
        __syncthreads();
        short8 a[4];
#pragma unroll
        for (int rt = 0; rt < 4; ++rt) {
            int row = rt * 16 + lr;
            a[rt] = *(const short8*)&As[row * 32 + ((lg ^ (row & 3)) * 8)];
        }
#pragma unroll
        for (int c2 = 0; c2 < 2; ++c2) {
            int ct = colb * 8 + w * 2 + c2;
            short8 B = *(const short8*)&pw[((size_t)(kb * nct + ct) * 64 + l) * 8];
#pragma unroll
            for (int rt = 0; rt < 4; ++rt)
                acc[rt][c2] = __builtin_amdgcn_mfma_f32_16x16x32_bf16(a[rt], B, acc[rt][c2], 0, 0, 0);
        }
        __syncthreads();
    }
#pragma unroll
    for (int c2 = 0; c2 < 2; ++c2) {
        int col = colb * 128 + w * 32 + c2 * 16 + lr;
        float bv = HASBIAS ? bias[col] : 0.f;
#pragma unroll
        for (int rt = 0; rt < 4; ++rt) {
            int rowb = row0 + rt * 16 + lg * 4;
#pragma unroll
            for (int reg = 0; reg < 4; ++reg) {
                int rr = rowb + reg;
                if (rr >= M) continue;
                float v = acc[rt][c2][reg] + bv;
                if (SILU) v = silu_f(v);
                if (OUTBF16) ((short*)Cv)[(size_t)rr * Nc + col] = f2b(v);
                else         ((float*)Cv)[(size_t)rr * Nc + col] = v;
            }
        }
    }
}

// ---------------------------------------------------------------------------
// Counting sort of edges by target
// ---------------------------------------------------------------------------
__global__ void deg_hist_kernel(const int* __restrict__ ei, int* __restrict__ deg_i, int E) {
    int e = blockIdx.x * 256 + threadIdx.x;
    if (e < E) atomicAdd(&deg_i[ei[e]], 1);
}

__global__ void scan_kernel(const int* __restrict__ deg_i, int* __restrict__ offs, int N) {
    __shared__ int s[256];
    int t = threadIdx.x;
    int chunk = (N + 255) / 256;
    int a = t * chunk, b = min(a + chunk, N);
    int sum = 0;
    for (int i = a; i < b; ++i) sum += deg_i[i];
    s[t] = sum;
    __syncthreads();
    for (int d = 1; d < 256; d <<= 1) {
        int v = (t >= d) ? s[t - d] : 0;
        __syncthreads();
        s[t] += v;
        __syncthreads();
    }
    int run = (t > 0) ? s[t - 1] : 0;
    for (int i = a; i < b; ++i) { offs[i] = run; run += deg_i[i]; }
}

__global__ void scatter_kernel(const int* __restrict__ ei, const int* __restrict__ offs,
                               int* __restrict__ counters, int* __restrict__ perm, int E) {
    int e = blockIdx.x * 256 + threadIdx.x;
    if (e < E) {
        int tg = ei[e];
        int pos = offs[tg] + atomicAdd(&counters[tg], 1);
        perm[pos] = e;
    }
}

// ---------------------------------------------------------------------------
// Segmented scan of a 64-row bf16 LDS plane down sorted targets (2 halves).
// ---------------------------------------------------------------------------
__device__ __forceinline__ void scan_plane(const short* __restrict__ sp,
                                           const int* __restrict__ s_tgt,
                                           float* __restrict__ dst,
                                           int rowstride, int coloff, int t)
{
    int col = t & 127;
    int r0 = (t >> 7) * 32;
    float acc = 0.f;
    int prev = s_tgt[r0];
    bool first = true;
    for (int i = r0; i < r0 + 32; ++i) {
        int tg = s_tgt[i];
        if (tg != prev) {
            if (prev >= 0) {
                float* d = dst + (size_t)prev * rowstride + coloff + col;
                if (first) atomicAdd(d, acc); else *d = acc;
            }
            acc = 0.f; prev = tg; first = false;
        }
        acc += b2f(sp[i * PSH + col]);
    }
    if (prev >= 0) atomicAdd(dst + (size_t)prev * rowstride + coloff + col, acc);
}

// ---------------------------------------------------------------------------
// Fused edge kernel (MFMA) over target-sorted edges; bf16 plane, bf16 gathers.
// ---------------------------------------------------------------------------
__global__ __launch_bounds__(256, 4) void edge_kernel(
    const int* __restrict__ ei, const int* __restrict__ perm,
    const float* __restrict__ rbf,
    const float* __restrict__ uv, const float* __restrict__ cutv,
    const short* __restrict__ pw1, const short* __restrict__ pw2,
    const float* __restrict__ bf1, const float* __restrict__ bf2,
    const short* __restrict__ x, const short* __restrict__ mu_b,
    float* __restrict__ scalar_msg, float* __restrict__ vector_msg,
    int E)
{
    __shared__ __align__(16) short s_h[64 * 128];      // bf16 h, XOR-swizzled
    __shared__ __align__(16) short s_plane[64 * PSH];  // bf16 plane (17.4 KB)
    __shared__ int   s_eid[TE];
    __shared__ int   s_tgt[TE];
    __shared__ int   s_src[TE];
    __shared__ float s_cut[TE];
    __shared__ float s_uv[TE * 3];

    const int t = threadIdx.x;
    const int w = t >> 6;
    const int l = t & 63;
    const int e0 = blockIdx.x * TE;

    // ---- metadata ----
    if (t < TE) {
        int p = e0 + t;
        int e = (p < E) ? perm[p] : -1;
        s_eid[t] = e;
        s_tgt[t] = (e >= 0) ? ei[e] : -1;
        s_src[t] = (e >= 0) ? ei[(size_t)E + e] : 0;
        s_cut[t] = (e >= 0) ? cutv[e] : 0.f;
    }
    __syncthreads();
    if (t < TE * 3) {
        int i = t / 3, c = t - i * 3;
        int e = s_eid[i];
        s_uv[t] = (e >= 0) ? uv[(size_t)e * 3 + c] : 0.f;
    }

    // ---- MFMA1: h = silu(rbf @ Wf1 + bf1) ----
    short8 Ar;
#pragma unroll
    for (int j = 0; j < 8; ++j) Ar[j] = 0;
    {
        int erow = w * 16 + (l & 15);
        int eidr = s_eid[erow];
        int g = l >> 4;
        if (eidr >= 0) {
            const float* rp = &rbf[(size_t)eidr * RDIM];
            if (g < 2) {
                float4 f0 = *(const float4*)&rp[g * 8];
                float4 f1 = *(const float4*)&rp[g * 8 + 4];
                Ar[0] = f2b(f0.x); Ar[1] = f2b(f0.y); Ar[2] = f2b(f0.z); Ar[3] = f2b(f0.w);
                Ar[4] = f2b(f1.x); Ar[5] = f2b(f1.y); Ar[6] = f2b(f1.z); Ar[7] = f2b(f1.w);
            } else if (g == 2) {
                float4 f0 = *(const float4*)&rp[16];
                Ar[0] = f2b(f0.x); Ar[1] = f2b(f0.y); Ar[2] = f2b(f0.z); Ar[3] = f2b(f0.w);
            }
        }
    }
    {
        f32x4 Hc[8];
#pragma unroll
        for (int ct = 0; ct < 8; ++ct) {
            f32x4 z = {0.f, 0.f, 0.f, 0.f};
            short8 Bw = *(const short8*)&pw1[(ct * 64 + l) * 8];
            Hc[ct] = __builtin_amdgcn_mfma_f32_16x16x32_bf16(Ar, Bw, z, 0, 0, 0);
        }
#pragma unroll
        for (int ct = 0; ct < 8; ++ct) {
            int colbase = ct * 16 + (l & 15);
            float b1 = bf1[colbase];
#pragma unroll
            for (int reg = 0; reg < 4; ++reg) {
                int rowg = w * 16 + ((l >> 4) * 4 + reg);
                float v = silu_f(Hc[ct][reg] + b1);
                s_h[rowg * 128 + (((colbase >> 3) ^ (rowg & 7)) * 8) + (colbase & 7)] = f2b(v);
            }
        }
    }
    __syncthreads();

    const int tj = t & 15, ti = t >> 4;
    const int j0 = tj * 8, i0 = ti * 4;

    // per-plane MFMA: plane p cols p*128..+127; wave strip 32 cols
    auto mfma_plane = [&](int p) {
        f32x4 C[4][2];
#pragma unroll
        for (int rt = 0; rt < 4; ++rt)
#pragma unroll
            for (int c2 = 0; c2 < 2; ++c2) C[rt][c2] = (f32x4){0.f, 0.f, 0.f, 0.f};
#pragma unroll
        for (int rt = 0; rt < 4; ++rt) {
            short8 A[4];
#pragma unroll
            for (int kb = 0; kb < 4; ++kb) {
                int row = rt * 16 + (l & 15);
                A[kb] = *(const short8*)&s_h[row * 128 + (((kb * 4 + (l >> 4)) ^ (row & 7)) * 8)];
            }
#pragma unroll
            for (int c2 = 0; c2 < 2; ++c2) {
                int ct = p * 8 + w * 2 + c2;
#pragma unroll
                for (int kb = 0; kb < 4; ++kb) {
                    short8 B = *(const short8*)&pw2[(((kb * 24 + ct) * 64 + l) * 8)];
                    C[rt][c2] = __builtin_amdgcn_mfma_f32_16x16x32_bf16(A[kb], B, C[rt][c2], 0, 0, 0);
                }
            }
        }
#pragma unroll
        for (int c2 = 0; c2 < 2; ++c2) {
            int colL = w * 32 + c2 * 16 + (l & 15);
            float bv = bf2[p * 128 + colL];
#pragma unroll
            for (int rt = 0; rt < 4; ++rt) {
#pragma unroll
                for (int reg = 0; reg < 4; ++reg) {
                    int rowg = rt * 16 + ((l >> 4) * 4 + reg);
                    s_plane[rowg * PSH + colL] = f2b((C[rt][c2][reg] + bv) * s_cut[rowg]);
                }
            }
        }
    };

    // ================= plane 0: filter_q -> scalar messages ================
    mfma_plane(0);
    __syncthreads();
#pragma unroll
    for (int r = 0; r < 4; ++r) {
        int i = i0 + r;
        int s = s_src[i];
        short8 pv = *(short8*)&s_plane[i * PSH + j0];
        short8 xv = *(const short8*)&x[(size_t)s * 384 + j0];
        short8 o;
#pragma unroll
        for (int c = 0; c < 8; ++c) o[c] = f2b(b2f(pv[c]) * b2f(xv[c]));
        *(short8*)&s_plane[i * PSH + j0] = o;
    }
    __syncthreads();
    scan_plane(s_plane, s_tgt, scalar_msg, HDIM, 0, t);
    __syncthreads();

    // ================= plane 1: filter_r -> vr =================
    mfma_plane(1);
    __syncthreads();
    float vr[4][8];
#pragma unroll
    for (int r = 0; r < 4; ++r) {
        int i = i0 + r;
        int s = s_src[i];
        short8 pv = *(short8*)&s_plane[i * PSH + j0];
        short8 xv = *(const short8*)&x[(size_t)s * 384 + 128 + j0];
#pragma unroll
        for (int c = 0; c < 8; ++c) vr[r][c] = b2f(pv[c]) * b2f(xv[c]);
    }
    __syncthreads();

    // ================= plane 2: filter_mu -> vm =================
    mfma_plane(2);
    __syncthreads();
    float vm[4][8];
#pragma unroll
    for (int r = 0; r < 4; ++r) {
        int i = i0 + r;
        int s = s_src[i];
        short8 pv = *(short8*)&s_plane[i * PSH + j0];
        short8 xv = *(const short8*)&x[(size_t)s * 384 + 256 + j0];
#pragma unroll
        for (int c = 0; c < 8; ++c) vm[r][c] = b2f(pv[c]) * b2f(xv[c]);
    }

    // ============ vector components x/y/z: combine + scan ============
#pragma unroll
    for (int comp = 0; comp < 3; ++comp) {
        if (comp > 0) __syncthreads();
#pragma unroll
        for (int r = 0; r < 4; ++r) {
            int i = i0 + r;
            int s = s_src[i];
            float u = s_uv[i * 3 + comp];
            short8 mv8 = *(const short8*)&mu_b[(size_t)s * 384 + comp * 128 + j0];
            short8 o;
#pragma unroll
            for (int c = 0; c < 8; ++c) o[c] = f2b(u * vr[r][c] + b2f(mv8[c]) * vm[r][c]);
            *(short8*)&s_plane[i * PSH + j0] = o;
        }
        __syncthreads();
        scan_plane(s_plane, s_tgt, vector_msg, 384, comp * 128, t);
    }
}

// ---------------------------------------------------------------------------
__global__ void node_update_kernel(const float* __restrict__ q, const float* __restrict__ mu,
    const float* __restrict__ scalar_msg, const float* __restrict__ vector_msg,
    const int* __restrict__ deg_i, float* __restrict__ outq, float* __restrict__ outmu,
    short* __restrict__ outmu_b, int N)
{
    int idx = blockIdx.x * 256 + threadIdx.x;
    if (idx >= N * HDIM) return;
    int n = idx >> 7, k = idx & 127;
    float inv = 1.0f / fmaxf((float)deg_i[n], 1.0f);
    outq[idx] = q[idx] + scalar_msg[idx] * inv;
#pragma unroll
    for (int c = 0; c < 3; ++c) {
        size_t o = ((size_t)n * 3 + c) * HDIM + k;
        float v = mu[o] + vector_msg[o] * inv;
        outmu[o] = v;
        outmu_b[o] = f2b(v);
    }
}

__global__ void si_kernel(const float* __restrict__ outq, const short* __restrict__ mu_cat,
                          short* __restrict__ si_b, int N)
{
    int idx = blockIdx.x * 256 + threadIdx.x;
    if (idx >= N * 256) return;
    int n = idx >> 8, j = idx & 255;
    if (j < 128) {
        si_b[idx] = f2b(outq[n * 128 + j]);
    } else {
        int k = j - 128;
        float s2 = 1e-8f;
#pragma unroll
        for (int c = 0; c < 3; ++c) {
            float v = b2f(mu_cat[((size_t)n * 3 + c) * 256 + k]);
            s2 += v * v;
        }
        si_b[idx] = f2b(sqrtf(s2));
    }
}

__global__ void final_kernel(const short* __restrict__ mu_cat, const float* __restrict__ delta,
                             float* __restrict__ outq, float* __restrict__ outmu, int N)
{
    int idx = blockIdx.x * 256 + threadIdx.x;
    if (idx >= N * HDIM) return;
    int n = idx >> 7, k = idx & 127;
    float inner = 0.f, mw[3];
#pragma unroll
    for (int c = 0; c < 3; ++c) {
        float mv = b2f(mu_cat[((size_t)n * 3 + c) * 256 + k]);
        mw[c] = b2f(mu_cat[((size_t)n * 3 + c) * 256 + 128 + k]);
        inner += mv * mw[c];
    }
    const float* dl = &delta[(size_t)n * 384];
    float dq = dl[k], dsc = dl[128 + k], dqm = dl[256 + k];
    outq[idx] += dq + dqm * inner;
#pragma unroll
    for (int c = 0; c < 3; ++c) {
        size_t o = ((size_t)n * 3 + c) * HDIM + k;
        outmu[o] += mw[c] * dsc;
    }
}

// ---------------------------------------------------------------------------
extern "C" void kernel_launch(void* const* d_in, const int* in_sizes, int n_in,
                              void* d_out, int out_size, void* d_ws, size_t ws_size,
                              hipStream_t stream)
{
    const float* q    = (const float*)d_in[0];
    const float* mu   = (const float*)d_in[1];
    const int*   ei   = (const int*)d_in[2];
    const float* rbf  = (const float*)d_in[3];
    const float* uv   = (const float*)d_in[4];
    const float* cutv = (const float*)d_in[5];
    const float* Wi1  = (const float*)d_in[6];
    const float* bi1  = (const float*)d_in[7];
    const float* Wi2  = (const float*)d_in[8];
    const float* bi2  = (const float*)d_in[9];
    const float* Wf1  = (const float*)d_in[10];
    const float* bf1  = (const float*)d_in[11];
    const float* Wf2  = (const float*)d_in[12];
    const float* bf2  = (const float*)d_in[13];
    const float* Wv   = (const float*)d_in[14];
    const float* Ws1  = (const float*)d_in[15];
    const float* bs1  = (const float*)d_in[16];
    const float* Ws2  = (const float*)d_in[17];
    const float* bs2  = (const float*)d_in[18];

    const int N = in_sizes[0] / HDIM;     // 10000
    const int E = in_sizes[2] / 2;        // 320000

    float* ws = (float*)d_ws;
    // [0,512N): scalar_msg(128N f32) + vector_msg(384N f32)  [edge phase]
    //           then: mu_cat bf16 [3N,256] (384N floats) + si_b bf16 (128N floats)
    float* scalar_msg = ws;
    float* vector_msg = ws + (size_t)N * 128;
    short* mu_cat     = (short*)ws;
    short* si_b       = (short*)(ws + (size_t)N * 384);
    // [512N,704N): xbuf bf16 [N,384]; after edge: t2 bf16 [N,384]
    short* xbuf       = (short*)(ws + (size_t)N * 512);
    short* t2         = (short*)(ws + (size_t)N * 512);
    // [704N,896N): t1 bf16 [N,384] (dead after GEMM2)
    short* t1         = (short*)(ws + (size_t)N * 704);
    // [896N,1088N): mu_b bf16 [N,3,128] (dead after edge)
    short* mu_b       = (short*)(ws + (size_t)N * 896);
    // [704N,1088N): delta f32 [N,384] (written by Ws2, after t1/mu_b dead)
    float* delta      = ws + (size_t)N * 704;
    // [1088N,1152N): q_b bf16 [N,128]
    short* q_b        = (short*)(ws + (size_t)N * 1088);
    // [1152N,1344N): outmu_b bf16 [3N,128]
    short* outmu_b    = (short*)(ws + (size_t)N * 1152);
    // [1344N,...): sort scratch + packed weights
    int*   ibase      = (int*)(ws + (size_t)N * 1344);
    int*   deg_i      = ibase;
    int*   counters   = ibase + N;
    int*   offs       = ibase + 2 * (size_t)N;
    int*   perm       = ibase + 3 * (size_t)N;
    short* pk         = (short*)(perm + E);
    short* pw1        = pk + OFF_PW1;
    short* pw2        = pk + OFF_PW2;

    float* outq  = (float*)d_out;
    float* outmu = (float*)d_out + (size_t)N * 128;

    hipMemsetAsync(ws, 0, (size_t)N * 512 * sizeof(float), stream);   // messages
    hipMemsetAsync(ibase, 0, (size_t)2 * N * sizeof(int), stream);    // deg + counters

    dim3 blk(256);
    int prep_items = PK_TOTAL + N * 512;
    prep_kernel<<<(prep_items + 255) / 256, blk, 0, stream>>>(Wf1, Wf2, Wi1, Wi2, Wv, Ws1, Ws2,
                                                              pk, q, mu, q_b, mu_b, N);

    // interaction node MLP: x = silu(q@Wi1+bi1)@Wi2+bi2
    gemm_mfma<true,  true, true><<<dim3((N + 63) / 64, 3), blk, 0, stream>>>(q_b, pk + OFF_PWI1, bi1, t1,   N, 128, 384);
    gemm_mfma<false, true, true><<<dim3((N + 63) / 64, 3), blk, 0, stream>>>(t1,  pk + OFF_PWI2, bi2, xbuf, N, 384, 384);

    // counting sort of edges by target
    deg_hist_kernel<<<(E + 255) / 256, blk, 0, stream>>>(ei, deg_i, E);
    scan_kernel<<<1, blk, 0, stream>>>(deg_i, offs, N);
    scatter_kernel<<<(E + 255) / 256, blk, 0, stream>>>(ei, offs, counters, perm, E);

    edge_kernel<<<(E + TE - 1) / TE, blk, 0, stream>>>(ei, perm, rbf, uv, cutv,
                                                       pw1, pw2, bf1, bf2,
                                                       xbuf, mu_b, scalar_msg, vector_msg, E);

    node_update_kernel<<<(N * HDIM + 255) / 256, blk, 0, stream>>>(q, mu, scalar_msg, vector_msg,
                                                                   deg_i, outq, outmu, outmu_b, N);
    // mixing
    gemm_mfma<false, false, true><<<dim3((3 * N + 63) / 64, 2), blk, 0, stream>>>(outmu_b, pk + OFF_PWV, nullptr, mu_cat, 3 * N, 128, 256);
    si_kernel<<<(N * 256 + 255) / 256, blk, 0, stream>>>(outq, mu_cat, si_b, N);
    gemm_mfma<true,  true, true><<<dim3((N + 63) / 64, 3), blk, 0, stream>>>(si_b, pk + OFF_PWS1, bs1, t2,    N, 256, 384);
    gemm_mfma<false, true, false><<<dim3((N + 63) / 64, 3), blk, 0, stream>>>(t2,  pk + OFF_PWS2, bs2, delta, N, 384, 384);
    final_kernel<<<(N * HDIM + 255) / 256, blk, 0, stream>>>(mu_cat, delta, outq, outmu, N);
}

// Round 6
// 299.574 us; speedup vs baseline: 15.7242x; 1.1491x over previous
//
#include <hip/hip_runtime.h>
#include <math.h>

#define HDIM 128
#define RDIM 20
#define TE 64
#define PT 72            // transposed plane stride in shorts (144 B rows)

typedef __attribute__((ext_vector_type(8))) short short8;
typedef __attribute__((ext_vector_type(4))) short s16x4;
typedef __attribute__((ext_vector_type(4))) float f32x4;

__device__ __forceinline__ float silu_f(float v) { return v / (1.0f + __expf(-v)); }

__device__ __forceinline__ short f2b(float x) {
    unsigned u = __float_as_uint(x);
    u += 0x7fffu + ((u >> 16) & 1u);
    return (short)(u >> 16);
}
__device__ __forceinline__ float b2f(short s) {
    return __uint_as_float(((unsigned)(unsigned short)s) << 16);
}
__device__ __forceinline__ unsigned cvt_pk_bf16(float a, float b) {
    unsigned r;
    asm("v_cvt_pk_bf16_f32 %0, %1, %2" : "=v"(r) : "v"(a), "v"(b));
    return r;   // low16 = bf16(a), high16 = bf16(b)
}

// ---------------------------------------------------------------------------
// Packed-weight segment offsets (bf16 elements)
// B-frag: lane l supplies B[k = kb*32 + (l>>4)*8 + j][col = ct*16 + (l&15)].
// ---------------------------------------------------------------------------
#define OFF_PW1   0
#define OFF_PW2   4096
#define OFF_PWI1  53248
#define OFF_PWI2  102400
#define OFF_PWV   249856
#define OFF_PWS1  282624
#define OFF_PWS2  380928
#define PK_TOTAL  528384

// prep: pack all weights + convert q, mu to bf16
__global__ void prep_kernel(const float* __restrict__ Wf1, const float* __restrict__ Wf2,
                            const float* __restrict__ Wi1, const float* __restrict__ Wi2,
                            const float* __restrict__ Wv,  const float* __restrict__ Ws1,
                            const float* __restrict__ Ws2, short* __restrict__ pk,
                            const float* __restrict__ q, const float* __restrict__ mu,
                            short* __restrict__ q_b, short* __restrict__ mu_b, int N)
{
    int t = blockIdx.x * 256 + threadIdx.x;
    if (t < PK_TOTAL) {
        const float* W; int Nc; int u; bool pad20 = false;
        if      (t < OFF_PW2)  { W = Wf1; Nc = 128; u = t;            pad20 = true; }
        else if (t < OFF_PWI1) { W = Wf2; Nc = 384; u = t - OFF_PW2;  }
        else if (t < OFF_PWI2) { W = Wi1; Nc = 384; u = t - OFF_PWI1; }
        else if (t < OFF_PWV)  { W = Wi2; Nc = 384; u = t - OFF_PWI2; }
        else if (t < OFF_PWS1) { W = Wv;  Nc = 256; u = t - OFF_PWV;  }
        else if (t < OFF_PWS2) { W = Ws1; Nc = 384; u = t - OFF_PWS1; }
        else                   { W = Ws2; Nc = 384; u = t - OFF_PWS2; }
        int j = u & 7, lane = (u >> 3) & 63, rest = u >> 9;
        int nct = Nc >> 4, ct = rest % nct, kb = rest / nct;
        int k = kb * 32 + ((lane >> 4) << 3) + j;
        int col = ct * 16 + (lane & 15);
        float v = (pad20 && k >= RDIM) ? 0.f : W[(size_t)k * Nc + col];
        pk[t] = f2b(v);
        return;
    }
    int u = t - PK_TOTAL;
    if (u < N * 128) { q_b[u] = f2b(q[u]); return; }
    u -= N * 128;
    if (u < N * 384) mu_b[u] = f2b(mu[u]);
}

// ---------------------------------------------------------------------------
// MFMA GEMM, bf16 A (pre-converted), pre-packed bf16 W.
// ---------------------------------------------------------------------------
template<bool SILU, bool HASBIAS, bool OUTBF16>
__global__ __launch_bounds__(256) void gemm_mfma(
    const short* __restrict__ A, const short* __restrict__ pw,
    const float* __restrict__ bias, void* __restrict__ Cv,
    int M, int K, int Nc)
{
    __shared__ short As[64 * 32];
    const int t = threadIdx.x, w = t >> 6, l = t & 63;
    const int lr = l & 15, lg = l >> 4;
    const int row0 = blockIdx.x * 64;
    const int colb = blockIdx.y;
    const int nct = Nc >> 4;
    f32x4 acc[4][2];
#pragma unroll
    for (int rt = 0; rt < 4; ++rt)
#pragma unroll
        for (int c2 = 0; c2 < 2; ++c2) acc[rt][c2] = (f32x4){0.f, 0.f, 0.f, 0.f};

    const int nkb = K >> 5;
    for (int kb = 0; kb < nkb; ++kb) {
        {
            int i = t >> 2, ch = t & 3;
            int row = row0 + i;
            short8 v = {0, 0, 0, 0, 0, 0, 0, 0};
            if (row < M) v = *(const short8*)&A[(size_t)row * K + kb * 32 + ch * 8];
            *(short8*)&As[i * 32 + ((ch ^ (i & 3)) * 8)] = v;
        }
        __syncthreads();
        short8 a[4];
#pragma unroll
        for (int rt = 0; rt < 4; ++rt) {
            int row = rt * 16 + lr;
            a[rt] = *(const short8*)&As[row * 32 + ((lg ^ (row & 3)) * 8)];
        }
#pragma unroll
        for (int c2 = 0; c2 < 2; ++c2) {
            int ct = colb * 8 + w * 2 + c2;
            short8 B = *(const short8*)&pw[((size_t)(kb * nct + ct) * 64 + l) * 8];
#pragma unroll
            for (int rt = 0; rt < 4; ++rt)
                acc[rt][c2] = __builtin_amdgcn_mfma_f32_16x16x32_bf16(a[rt], B, acc[rt][c2], 0, 0, 0);
        }
        __syncthreads();
    }
#pragma unroll
    for (int c2 = 0; c2 < 2; ++c2) {
        int col = colb * 128 + w * 32 + c2 * 16 + lr;
        float bv = HASBIAS ? bias[col] : 0.f;
#pragma unroll
        for (int rt = 0; rt < 4; ++rt) {
            int rowb = row0 + rt * 16 + lg * 4;
#pragma unroll
            for (int reg = 0; reg < 4; ++reg) {
                int rr = rowb + reg;
                if (rr >= M) continue;
                float v = acc[rt][c2][reg] + bv;
                if (SILU) v = silu_f(v);
                if (OUTBF16) ((short*)Cv)[(size_t)rr * Nc + col] = f2b(v);
                else         ((float*)Cv)[(size_t)rr * Nc + col] = v;
            }
        }
    }
}

// ---------------------------------------------------------------------------
// Counting sort of edges by target
// ---------------------------------------------------------------------------
__global__ void deg_hist_kernel(const int* __restrict__ ei, int* __restrict__ deg_i, int E) {
    int e = blockIdx.x * 256 + threadIdx.x;
    if (e < E) atomicAdd(&deg_i[ei[e]], 1);
}

__global__ void scan_kernel(const int* __restrict__ deg_i, int* __restrict__ offs, int N) {
    __shared__ int s[256];
    int t = threadIdx.x;
    int chunk = (N + 255) / 256;
    int a = t * chunk, b = min(a + chunk, N);
    int sum = 0;
    for (int i = a; i < b; ++i) sum += deg_i[i];
    s[t] = sum;
    __syncthreads();
    for (int d = 1; d < 256; d <<= 1) {
        int v = (t >= d) ? s[t - d] : 0;
        __syncthreads();
        s[t] += v;
        __syncthreads();
    }
    int run = (t > 0) ? s[t - 1] : 0;
    for (int i = a; i < b; ++i) { offs[i] = run; run += deg_i[i]; }
}

__global__ void scatter_kernel(const int* __restrict__ ei, const int* __restrict__ offs,
                               int* __restrict__ counters, int* __restrict__ perm, int E) {
    int e = blockIdx.x * 256 + threadIdx.x;
    if (e < E) {
        int tg = ei[e];
        int pos = offs[tg] + atomicAdd(&counters[tg], 1);
        perm[pos] = e;
    }
}

// ---------------------------------------------------------------------------
// Segmented scan of the TRANSPOSED bf16 plane [col][row] down sorted targets.
// Boundary bits in a uniform 32-bit mask (scalar-pipe tests).
// ---------------------------------------------------------------------------
__device__ __forceinline__ void scan_T(const short* __restrict__ s_pt,
                                       const int* __restrict__ s_tgt,
                                       unsigned bm32, float* __restrict__ dst,
                                       int rowstride, int coloff, int t)
{
    int col = t & 127;
    int r0 = (t >> 7) * 32;
    const short* cp = &s_pt[col * PT + r0];
    float acc = 0.f;
    bool first = (bm32 & 1u) ? false : true;
#pragma unroll
    for (int g = 0; g < 4; ++g) {
        short8 v = *(const short8*)&cp[g * 8];
#pragma unroll
        for (int kk = 0; kk < 8; ++kk) {
            const int k = g * 8 + kk;
            if (k > 0 && ((bm32 >> k) & 1u)) {
                int tg = s_tgt[r0 + k - 1];
                if (tg >= 0) {
                    float* d = dst + (size_t)tg * rowstride + coloff + col;
                    if (first) atomicAdd(d, acc); else *d = acc;
                }
                acc = 0.f; first = false;
            }
            acc += b2f(v[kk]);
        }
    }
    int tg = s_tgt[r0 + 31];
    if (tg >= 0) atomicAdd(dst + (size_t)tg * rowstride + coloff + col, acc);
}

// ---------------------------------------------------------------------------
// Fused edge kernel (MFMA) over target-sorted edges; transposed bf16 plane.
// ---------------------------------------------------------------------------
__global__ __launch_bounds__(256, 4) void edge_kernel(
    const int* __restrict__ ei, const int* __restrict__ perm,
    const float* __restrict__ rbf,
    const float* __restrict__ uv, const float* __restrict__ cutv,
    const short* __restrict__ pw1, const short* __restrict__ pw2,
    const float* __restrict__ bf1, const float* __restrict__ bf2,
    const short* __restrict__ x, const short* __restrict__ mu_b,
    float* __restrict__ scalar_msg, float* __restrict__ vector_msg,
    int E)
{
    __shared__ __align__(16) short s_h[64 * 128];     // bf16 h, XOR-swizzled (16 KB)
    __shared__ __align__(16) short s_pt[128 * PT];    // transposed plane (18 KB)
    __shared__ int   s_eid[TE];
    __shared__ int   s_tgt[TE];
    __shared__ int   s_src[TE];
    __shared__ float s_cut[TE];
    __shared__ float s_uv[TE * 3];

    const int t = threadIdx.x;
    const int w = t >> 6;
    const int l = t & 63;
    const int e0 = blockIdx.x * TE;

    // ---- metadata ----
    if (t < TE) {
        int p = e0 + t;
        int e = (p < E) ? perm[p] : -1;
        s_eid[t] = e;
        s_tgt[t] = (e >= 0) ? ei[e] : -1;
        s_src[t] = (e >= 0) ? ei[(size_t)E + e] : 0;
        s_cut[t] = (e >= 0) ? cutv[e] : 0.f;
    }
    __syncthreads();
    if (t < TE * 3) {
        int i = t / 3, c = t - i * 3;
        int e = s_eid[i];
        s_uv[t] = (e >= 0) ? uv[(size_t)e * 3 + c] : 0.f;
    }
    // boundary mask (uniform, per-wave ballot over LDS tgt)
    bool bp = (l > 0) && (s_tgt[l] != s_tgt[l - 1]);
    unsigned long long bl = __ballot(bp);
    unsigned bmlo = __builtin_amdgcn_readfirstlane((unsigned)bl);
    unsigned bmhi = __builtin_amdgcn_readfirstlane((unsigned)(bl >> 32));

    // ---- MFMA1: h = silu(rbf @ Wf1 + bf1) ----
    short8 Ar;
#pragma unroll
    for (int j = 0; j < 8; ++j) Ar[j] = 0;
    {
        int erow = w * 16 + (l & 15);
        int eidr = s_eid[erow];
        int g = l >> 4;
        if (eidr >= 0) {
            const float* rp = &rbf[(size_t)eidr * RDIM];
            if (g < 2) {
                float4 f0 = *(const float4*)&rp[g * 8];
                float4 f1 = *(const float4*)&rp[g * 8 + 4];
                Ar[0] = f2b(f0.x); Ar[1] = f2b(f0.y); Ar[2] = f2b(f0.z); Ar[3] = f2b(f0.w);
                Ar[4] = f2b(f1.x); Ar[5] = f2b(f1.y); Ar[6] = f2b(f1.z); Ar[7] = f2b(f1.w);
            } else if (g == 2) {
                float4 f0 = *(const float4*)&rp[16];
                Ar[0] = f2b(f0.x); Ar[1] = f2b(f0.y); Ar[2] = f2b(f0.z); Ar[3] = f2b(f0.w);
            }
        }
    }
    {
        f32x4 Hc[8];
#pragma unroll
        for (int ct = 0; ct < 8; ++ct) {
            f32x4 z = {0.f, 0.f, 0.f, 0.f};
            short8 Bw = *(const short8*)&pw1[(ct * 64 + l) * 8];
            Hc[ct] = __builtin_amdgcn_mfma_f32_16x16x32_bf16(Ar, Bw, z, 0, 0, 0);
        }
#pragma unroll
        for (int ct = 0; ct < 8; ++ct) {
            int colbase = ct * 16 + (l & 15);
            float b1 = bf1[colbase];
#pragma unroll
            for (int reg = 0; reg < 4; ++reg) {
                int rowg = w * 16 + ((l >> 4) * 4 + reg);
                float v = silu_f(Hc[ct][reg] + b1);
                s_h[rowg * 128 + (((colbase >> 3) ^ (rowg & 7)) * 8) + (colbase & 7)] = f2b(v);
            }
        }
    }
    __syncthreads();

    // diagonal combine mapping: 8 cols x 4 rows per thread, bank-spread
    const int tj = t & 15, ti = t >> 4;
    const int c0 = tj * 8;
    const int r0d = 4 * ((ti + tj) & 15);

    // per-plane MFMA (k-outer, B hoisted); epilogue -> transposed plane
    auto mfma_plane = [&](int p) {
        f32x4 C[4][2];
#pragma unroll
        for (int rt = 0; rt < 4; ++rt)
#pragma unroll
            for (int c2 = 0; c2 < 2; ++c2) C[rt][c2] = (f32x4){0.f, 0.f, 0.f, 0.f};
#pragma unroll
        for (int kb = 0; kb < 4; ++kb) {
            short8 A[4];
#pragma unroll
            for (int rt = 0; rt < 4; ++rt) {
                int row = rt * 16 + (l & 15);
                A[rt] = *(const short8*)&s_h[row * 128 + (((kb * 4 + (l >> 4)) ^ (row & 7)) * 8)];
            }
#pragma unroll
            for (int c2 = 0; c2 < 2; ++c2) {
                int ct = p * 8 + w * 2 + c2;
                short8 B = *(const short8*)&pw2[(((kb * 24 + ct) * 64 + l) * 8)];
#pragma unroll
                for (int rt = 0; rt < 4; ++rt)
                    C[rt][c2] = __builtin_amdgcn_mfma_f32_16x16x32_bf16(A[rt], B, C[rt][c2], 0, 0, 0);
            }
        }
        const int lg = l >> 4;
#pragma unroll
        for (int c2 = 0; c2 < 2; ++c2) {
            int colL = w * 32 + c2 * 16 + (l & 15);
            float bv = bf2[p * 128 + colL];
#pragma unroll
            for (int rt = 0; rt < 4; ++rt) {
                float4 cu4 = *(float4*)&s_cut[rt * 16 + lg * 4];
                float v0 = (C[rt][c2][0] + bv) * cu4.x;
                float v1 = (C[rt][c2][1] + bv) * cu4.y;
                float v2 = (C[rt][c2][2] + bv) * cu4.z;
                float v3 = (C[rt][c2][3] + bv) * cu4.w;
                *(uint2*)&s_pt[colL * PT + rt * 16 + lg * 4] =
                    make_uint2(cvt_pk_bf16(v0, v1), cvt_pk_bf16(v2, v3));
            }
        }
    };

    // ================= plane 0: filter_q -> scalar messages ================
    mfma_plane(0);
    __syncthreads();
    {
        float xf[4][8];
#pragma unroll
        for (int rr = 0; rr < 4; ++rr) {
            int s = s_src[r0d + rr];
            short8 xv = *(const short8*)&x[(size_t)s * 384 + c0];
#pragma unroll
            for (int c = 0; c < 8; ++c) xf[rr][c] = b2f(xv[c]);
        }
#pragma unroll
        for (int cc = 0; cc < 8; ++cc) {
            short* pp = &s_pt[(c0 + cc) * PT + r0d];
            s16x4 pv = *(s16x4*)pp;
            float o0 = b2f(pv[0]) * xf[0][cc];
            float o1 = b2f(pv[1]) * xf[1][cc];
            float o2 = b2f(pv[2]) * xf[2][cc];
            float o3 = b2f(pv[3]) * xf[3][cc];
            *(uint2*)pp = make_uint2(cvt_pk_bf16(o0, o1), cvt_pk_bf16(o2, o3));
        }
    }
    __syncthreads();
    scan_T(s_pt, s_tgt, (t >> 7) ? bmhi : bmlo, scalar_msg, HDIM, 0, t);
    __syncthreads();

    // ================= plane 1: filter_r -> vr =================
    mfma_plane(1);
    __syncthreads();
    float vr[4][8];
    {
        float xf[4][8];
#pragma unroll
        for (int rr = 0; rr < 4; ++rr) {
            int s = s_src[r0d + rr];
            short8 xv = *(const short8*)&x[(size_t)s * 384 + 128 + c0];
#pragma unroll
            for (int c = 0; c < 8; ++c) xf[rr][c] = b2f(xv[c]);
        }
#pragma unroll
        for (int cc = 0; cc < 8; ++cc) {
            s16x4 pv = *(const s16x4*)&s_pt[(c0 + cc) * PT + r0d];
#pragma unroll
            for (int rr = 0; rr < 4; ++rr) vr[rr][cc] = b2f(pv[rr]) * xf[rr][cc];
        }
    }
    __syncthreads();

    // ================= plane 2: filter_mu -> vm =================
    mfma_plane(2);
    __syncthreads();
    float vm[4][8];
    {
        float xf[4][8];
#pragma unroll
        for (int rr = 0; rr < 4; ++rr) {
            int s = s_src[r0d + rr];
            short8 xv = *(const short8*)&x[(size_t)s * 384 + 256 + c0];
#pragma unroll
            for (int c = 0; c < 8; ++c) xf[rr][c] = b2f(xv[c]);
        }
#pragma unroll
        for (int cc = 0; cc < 8; ++cc) {
            s16x4 pv = *(const s16x4*)&s_pt[(c0 + cc) * PT + r0d];
#pragma unroll
            for (int rr = 0; rr < 4; ++rr) vm[rr][cc] = b2f(pv[rr]) * xf[rr][cc];
        }
    }

    // ============ vector components x/y/z: combine + scan ============
#pragma unroll
    for (int comp = 0; comp < 3; ++comp) {
        if (comp > 0) __syncthreads();   // previous scan's reads must finish
        float uvv[4], mf[4][8];
#pragma unroll
        for (int rr = 0; rr < 4; ++rr) {
            uvv[rr] = s_uv[(r0d + rr) * 3 + comp];
            int s = s_src[r0d + rr];
            short8 mv = *(const short8*)&mu_b[(size_t)s * 384 + comp * 128 + c0];
#pragma unroll
            for (int c = 0; c < 8; ++c) mf[rr][c] = b2f(mv[c]);
        }
#pragma unroll
        for (int cc = 0; cc < 8; ++cc) {
            float o0 = fmaf(uvv[0], vr[0][cc], mf[0][cc] * vm[0][cc]);
            float o1 = fmaf(uvv[1], vr[1][cc], mf[1][cc] * vm[1][cc]);
            float o2 = fmaf(uvv[2], vr[2][cc], mf[2][cc] * vm[2][cc]);
            float o3 = fmaf(uvv[3], vr[3][cc], mf[3][cc] * vm[3][cc]);
            *(uint2*)&s_pt[(c0 + cc) * PT + r0d] =
                make_uint2(cvt_pk_bf16(o0, o1), cvt_pk_bf16(o2, o3));
        }
        __syncthreads();
        scan_T(s_pt, s_tgt, (t >> 7) ? bmhi : bmlo, vector_msg, 384, comp * 128, t);
    }
}

// ---------------------------------------------------------------------------
__global__ void node_update_kernel(const float* __restrict__ q, const float* __restrict__ mu,
    const float* __restrict__ scalar_msg, const float* __restrict__ vector_msg,
    const int* __restrict__ deg_i, float* __restrict__ outq, float* __restrict__ outmu,
    short* __restrict__ outmu_b, int N)
{
    int idx = blockIdx.x * 256 + threadIdx.x;
    if (idx >= N * HDIM) return;
    int n = idx >> 7, k = idx & 127;
    float inv = 1.0f / fmaxf((float)deg_i[n], 1.0f);
    outq[idx] = q[idx] + scalar_msg[idx] * inv;
#pragma unroll
    for (int c = 0; c < 3; ++c) {
        size_t o = ((size_t)n * 3 + c) * HDIM + k;
        float v = mu[o] + vector_msg[o] * inv;
        outmu[o] = v;
        outmu_b[o] = f2b(v);
    }
}

__global__ void si_kernel(const float* __restrict__ outq, const short* __restrict__ mu_cat,
                          short* __restrict__ si_b, int N)
{
    int idx = blockIdx.x * 256 + threadIdx.x;
    if (idx >= N * 256) return;
    int n = idx >> 8, j = idx & 255;
    if (j < 128) {
        si_b[idx] = f2b(outq[n * 128 + j]);
    } else {
        int k = j - 128;
        float s2 = 1e-8f;
#pragma unroll
        for (int c = 0; c < 3; ++c) {
            float v = b2f(mu_cat[((size_t)n * 3 + c) * 256 + k]);
            s2 += v * v;
        }
        si_b[idx] = f2b(sqrtf(s2));
    }
}

__global__ void final_kernel(const short* __restrict__ mu_cat, const float* __restrict__ delta,
                             float* __restrict__ outq, float* __restrict__ outmu, int N)
{
    int idx = blockIdx.x * 256 + threadIdx.x;
    if (idx >= N * HDIM) return;
    int n = idx >> 7, k = idx & 127;
    float inner = 0.f, mw[3];
#pragma unroll
    for (int c = 0; c < 3; ++c) {
        float mv = b2f(mu_cat[((size_t)n * 3 + c) * 256 + k]);
        mw[c] = b2f(mu_cat[((size_t)n * 3 + c) * 256 + 128 + k]);
        inner += mv * mw[c];
    }
    const float* dl = &delta[(size_t)n * 384];
    float dq = dl[k], dsc = dl[128 + k], dqm = dl[256 + k];
    outq[idx] += dq + dqm * inner;
#pragma unroll
    for (int c = 0; c < 3; ++c) {
        size_t o = ((size_t)n * 3 + c) * HDIM + k;
        outmu[o] += mw[c] * dsc;
    }
}

// ---------------------------------------------------------------------------
extern "C" void kernel_launch(void* const* d_in, const int* in_sizes, int n_in,
                              void* d_out, int out_size, void* d_ws, size_t ws_size,
                              hipStream_t stream)
{
    const float* q    = (const float*)d_in[0];
    const float* mu   = (const float*)d_in[1];
    const int*   ei   = (const int*)d_in[2];
    const float* rbf  = (const float*)d_in[3];
    const float* uv   = (const float*)d_in[4];
    const float* cutv = (const float*)d_in[5];
    const float* Wi1  = (const float*)d_in[6];
    const float* bi1  = (const float*)d_in[7];
    const float* Wi2  = (const float*)d_in[8];
    const float* bi2  = (const float*)d_in[9];
    const float* Wf1  = (const float*)d_in[10];
    const float* bf1  = (const float*)d_in[11];
    const float* Wf2  = (const float*)d_in[12];
    const float* bf2  = (const float*)d_in[13];
    const float* Wv   = (const float*)d_in[14];
    const float* Ws1  = (const float*)d_in[15];
    const float* bs1  = (const float*)d_in[16];
    const float* Ws2  = (const float*)d_in[17];
    const float* bs2  = (const float*)d_in[18];

    const int N = in_sizes[0] / HDIM;     // 10000
    const int E = in_sizes[2] / 2;        // 320000

    float* ws = (float*)d_ws;
    // [0,512N): scalar_msg(128N f32) + vector_msg(384N f32)  [edge phase]
    //           then: mu_cat bf16 [3N,256] + si_b bf16
    float* scalar_msg = ws;
    float* vector_msg = ws + (size_t)N * 128;
    short* mu_cat     = (short*)ws;
    short* si_b       = (short*)(ws + (size_t)N * 384);
    // [512N,704N): xbuf bf16 [N,384]; after edge: t2 bf16 [N,384]
    short* xbuf       = (short*)(ws + (size_t)N * 512);
    short* t2         = (short*)(ws + (size_t)N * 512);
    // [704N,896N): t1 bf16 [N,384] (dead after GEMM2)
    short* t1         = (short*)(ws + (size_t)N * 704);
    // [896N,1088N): mu_b bf16 (dead after edge)
    short* mu_b       = (short*)(ws + (size_t)N * 896);
    // [704N,1088N): delta f32 (written after t1/mu_b dead)
    float* delta      = ws + (size_t)N * 704;
    // [1088N,1152N): q_b bf16
    short* q_b        = (short*)(ws + (size_t)N * 1088);
    // [1152N,1344N): outmu_b bf16
    short* outmu_b    = (short*)(ws + (size_t)N * 1152);
    // [1344N,...): sort scratch + packed weights
    int*   ibase      = (int*)(ws + (size_t)N * 1344);
    int*   deg_i      = ibase;
    int*   counters   = ibase + N;
    int*   offs       = ibase + 2 * (size_t)N;
    int*   perm       = ibase + 3 * (size_t)N;
    short* pk         = (short*)(perm + E);
    short* pw1        = pk + OFF_PW1;
    short* pw2        = pk + OFF_PW2;

    float* outq  = (float*)d_out;
    float* outmu = (float*)d_out + (size_t)N * 128;

    hipMemsetAsync(ws, 0, (size_t)N * 512 * sizeof(float), stream);   // messages
    hipMemsetAsync(ibase, 0, (size_t)2 * N * sizeof(int), stream);    // deg + counters

    dim3 blk(256);
    int prep_items = PK_TOTAL + N * 512;
    prep_kernel<<<(prep_items + 255) / 256, blk, 0, stream>>>(Wf1, Wf2, Wi1, Wi2, Wv, Ws1, Ws2,
                                                              pk, q, mu, q_b, mu_b, N);

    // interaction node MLP: x = silu(q@Wi1+bi1)@Wi2+bi2
    gemm_mfma<true,  true, true><<<dim3((N + 63) / 64, 3), blk, 0, stream>>>(q_b, pk + OFF_PWI1, bi1, t1,   N, 128, 384);
    gemm_mfma<false, true, true><<<dim3((N + 63) / 64, 3), blk, 0, stream>>>(t1,  pk + OFF_PWI2, bi2, xbuf, N, 384, 384);

    // counting sort of edges by target
    deg_hist_kernel<<<(E + 255) / 256, blk, 0, stream>>>(ei, deg_i, E);
    scan_kernel<<<1, blk, 0, stream>>>(deg_i, offs, N);
    scatter_kernel<<<(E + 255) / 256, blk, 0, stream>>>(ei, offs, counters, perm, E);

    edge_kernel<<<(E + TE - 1) / TE, blk, 0, stream>>>(ei, perm, rbf, uv, cutv,
                                                       pw1, pw2, bf1, bf2,
                                                       xbuf, mu_b, scalar_msg, vector_msg, E);

    node_update_kernel<<<(N * HDIM + 255) / 256, blk, 0, stream>>>(q, mu, scalar_msg, vector_msg,
                                                                   deg_i, outq, outmu, outmu_b, N);
    // mixing
    gemm_mfma<false, false, true><<<dim3((3 * N + 63) / 64, 2), blk, 0, stream>>>(outmu_b, pk + OFF_PWV, nullptr, mu_cat, 3 * N, 128, 256);
    si_kernel<<<(N * 256 + 255) / 256, blk, 0, stream>>>(outq, mu_cat, si_b, N);
    gemm_mfma<true,  true, true><<<dim3((N + 63) / 64, 3), blk, 0, stream>>>(si_b, pk + OFF_PWS1, bs1, t2,    N, 256, 384);
    gemm_mfma<false, true, false><<<dim3((N + 63) / 64, 3), blk, 0, stream>>>(t2,  pk + OFF_PWS2, bs2, delta, N, 384, 384);
    final_kernel<<<(N * HDIM + 255) / 256, blk, 0, stream>>>(mu_cat, delta, outq, outmu, N);
}